// Round 14
// baseline (354.564 us; speedup 1.0000x reference)
//
#include <hip/hip_runtime.h>
#include <hip/hip_bf16.h>

typedef unsigned short u16;
typedef __attribute__((ext_vector_type(8))) short s16x8;
typedef __attribute__((ext_vector_type(4))) short s16x4;
typedef __attribute__((ext_vector_type(4))) float f32x4;

#define SEQ 1024
#define BATCH 2
#define HID 1024
#define NHEAD 16
#define NKVH 4
#define HDIM 64
#define NEXP 8
#define FFN 2048
#define TOK (SEQ*BATCH)
#define QKVO ((NHEAD + 2*NKVH)*HDIM)   // 1536
#define NPART 144                       // 32-row q-tiles, 128-row kv chunks
#define PREC 2112                       // 32*64 o + 32 m + 32 l

// async global->LDS, 16B per lane, dest = uniform base + lane*16
#define GL16(gp, lp) __builtin_amdgcn_global_load_lds( \
    (const __attribute__((address_space(1))) unsigned int*)(gp), \
    (__attribute__((address_space(3))) unsigned int*)(lp), 16, 0, 0)

__device__ __forceinline__ float b2f(u16 u) {
    unsigned int x = ((unsigned int)u) << 16;
    return __uint_as_float(x);
}
__device__ __forceinline__ u16 f2b(float f) {
    unsigned int x = __float_as_uint(f);
    x = (x + 0x7FFFu + ((x >> 16) & 1u)) >> 16;
    return (u16)x;
}
__device__ __forceinline__ void split2(float x, u16& hi, u16& lo) {
    hi = f2b(x);
    lo = f2b(x - b2f(hi));
}
__device__ __forceinline__ f32x4 mfma16(s16x8 a, s16x8 b, f32x4 c) {
    return __builtin_amdgcn_mfma_f32_16x16x32_bf16(a, b, c, 0, 0, 0);
}
__device__ __forceinline__ float gelu_t(float x) {
    float x3 = x * x * x;
    return 0.5f * x * (1.0f + tanhf(0.7978845608028654f * (x + 0.044715f * x3)));
}

// ------- LayerNorm: f32 in; OUTMODE: 0=f32, 2=hi/lo, 3=f32+hi/lo, 4=f32+hi -
template<int OUTMODE>
__global__ __launch_bounds__(256) void ln_k(const float* __restrict__ xin,
    const float* __restrict__ wgt, const float* __restrict__ bia,
    float* __restrict__ outf, u16* __restrict__ outh, u16* __restrict__ outl)
{
    __shared__ float red[8];
    const int t = blockIdx.x, tid = threadIdx.x;
    f32x4 u = *((const f32x4*)(xin + (size_t)t * HID) + tid);
    float s = u[0] + u[1] + u[2] + u[3];
    #pragma unroll
    for (int off = 32; off >= 1; off >>= 1) s += __shfl_xor(s, off);
    if ((tid & 63) == 0) red[tid >> 6] = s;
    __syncthreads();
    float mu = (red[0] + red[1] + red[2] + red[3]) * (1.0f / HID);
    float d0 = u[0]-mu, d1 = u[1]-mu, d2 = u[2]-mu, d3 = u[3]-mu;
    float ss = d0*d0 + d1*d1 + d2*d2 + d3*d3;
    #pragma unroll
    for (int off = 32; off >= 1; off >>= 1) ss += __shfl_xor(ss, off);
    if ((tid & 63) == 0) red[4 + (tid >> 6)] = ss;
    __syncthreads();
    float var = (red[4] + red[5] + red[6] + red[7]) * (1.0f / HID);
    float rs = 1.0f / sqrtf(var + 1e-5f);
    f32x4 wv = *((const f32x4*)wgt + tid);
    f32x4 bv = *((const f32x4*)bia + tid);
    f32x4 o;
    o[0] = d0*rs*wv[0] + bv[0];
    o[1] = d1*rs*wv[1] + bv[1];
    o[2] = d2*rs*wv[2] + bv[2];
    o[3] = d3*rs*wv[3] + bv[3];
    if (OUTMODE == 0 || OUTMODE >= 3)
        *((f32x4*)(outf + (size_t)t * HID) + tid) = o;
    if (OUTMODE == 2 || OUTMODE == 3) {
        s16x4 h, l;
        #pragma unroll
        for (int j = 0; j < 4; ++j) {
            u16 hb, lb; split2(o[j], hb, lb);
            h[j] = (short)hb; l[j] = (short)lb;
        }
        *((s16x4*)(outh + (size_t)t * HID) + tid) = h;
        *((s16x4*)(outl + (size_t)t * HID) + tid) = l;
    }
    if (OUTMODE == 4) {
        s16x4 h;
        #pragma unroll
        for (int j = 0; j < 4; ++j) h[j] = (short)f2b(o[j]);
        *((s16x4*)(outh + (size_t)t * HID) + tid) = h;
    }
}

// -------- weight prep: split-cast f32 -> bf16 hi/lo (same layout) ----
__global__ __launch_bounds__(256) void split_cast_k(const float* __restrict__ in,
    u16* __restrict__ hi, u16* __restrict__ lo)
{
    int i = blockIdx.x * 256 + threadIdx.x;
    f32x4 v = ((const f32x4*)in)[i];
    s16x4 h, l;
    #pragma unroll
    for (int j = 0; j < 4; ++j) {
        u16 hb, lb; split2(v[j], hb, lb);
        h[j] = (short)hb; l[j] = (short)lb;
    }
    ((s16x4*)hi)[i] = h;
    ((s16x4*)lo)[i] = l;
}

// -------- weight prep: transpose-cast f32 [E][R][C] -> bf16 [E][C][R]
__global__ __launch_bounds__(256) void trans_cast_k(const float* __restrict__ in,
    u16* __restrict__ out, int R, int C)
{
    __shared__ float tile[64][65];
    const int e = blockIdx.z;
    const float* src = in + (size_t)e * R * C;
    u16* dst = out + (size_t)e * C * R;
    const int r0 = blockIdx.y * 64, c0 = blockIdx.x * 64;
    const int tr = threadIdx.x >> 2, tc = (threadIdx.x & 3) * 16;
    #pragma unroll
    for (int j = 0; j < 4; ++j) {
        f32x4 v = *(const f32x4*)(src + (size_t)(r0 + tr) * C + c0 + tc + j * 4);
        *(f32x4*)&tile[tr][tc + j * 4] = v;
    }
    __syncthreads();
    s16x8 o0, o1;
    #pragma unroll
    for (int j = 0; j < 8; ++j) o0[j] = (short)f2b(tile[tc + j][tr]);
    #pragma unroll
    for (int j = 0; j < 8; ++j) o1[j] = (short)f2b(tile[tc + 8 + j][tr]);
    u16* dp = dst + (size_t)(c0 + tr) * R + r0 + tc;
    *(s16x8*)dp = o0;
    *(s16x8*)(dp + 8) = o1;
}

// ------ gemm_db: bf16 MFMA GEMM, global_load_lds + double buffer -----
// C[m,n] = sum_k A[m,k]*B[n,k]; A,B row-major [.,K] bf16 hi(/lo).
// TERMS: 1 = AhBh ; 2 = + AlBh ; 3 = + AhBl
// AMODE: 0 plain rows; 1 gather rows glist[off+r]; 2 contiguous off+r
// EPI: 0 f32; 1 f32+RES; 2 bf16(gelu); 4 f32+RES dual; 5 bf16 plain
// TILE: 0 = 128x128 (waves 2x2); 1 = 128x64 (waves 4x1); 2 = 64x64 (waves 4x1)
// KU: K-chunks (x32) staged per barrier iteration (1 or 2)
template<int AMODE, int TERMS, int EPI, int TILE, int KU>
__global__ __launch_bounds__(256, 2) void gemm_db(
    const u16* __restrict__ Ah, const u16* __restrict__ Al,
    const u16* __restrict__ Bh, const u16* __restrict__ Bl,
    void* __restrict__ Cv, const float* __restrict__ RES, float* __restrict__ C2,
    const int* __restrict__ glist, const int* __restrict__ offs,
    const int* __restrict__ cnts, const float* __restrict__ slot_p,
    int M, int N, int K, int lda, int ldb, int ldc, long long bStrideE)
{
    constexpr int BM = (TILE == 2) ? 64 : 128;
    constexpr int BN = (TILE == 0) ? 128 : 64;
    constexpr int MI = (TILE == 0) ? 4 : ((TILE == 1) ? 2 : 1);
    constexpr bool A2 = (BM == 128);
    constexpr bool B2 = (BN == 128);
    __shared__ u16 AHs[2][KU][BM][32];
    __shared__ u16 ALs[(TERMS >= 2) ? 2 : 1][(TERMS >= 2) ? KU : 1][(TERMS >= 2) ? BM : 1][32];
    __shared__ u16 BHs[2][KU][BN][32];
    __shared__ u16 BLs[(TERMS >= 3) ? 2 : 1][(TERMS >= 3) ? KU : 1][(TERMS >= 3) ? BN : 1][32];

    const int tid = threadIdx.x;
    const int m0 = blockIdx.y * BM;
    const int n0 = blockIdx.x * BN;
    int off = 0, cnt = M;
    if (AMODE != 0) {
        const int e = blockIdx.z;
        off = offs[e]; cnt = cnts[e];
        if (m0 >= cnt) return;
        long long be = (long long)e * bStrideE;
        Bh += be;
        if (TERMS >= 3) Bl += be;
    }
    const int lane = tid & 63, w = tid >> 6;
    const int wmB = (TILE == 0) ? ((w >> 1) * 64) : (w * (BM / 4));
    const int wnB = (TILE == 0) ? ((w & 1) * 64) : 0;
    const int l16 = lane & 15, grp = lane >> 4;
    const int srow = lane >> 2, schk = (lane & 3) * 8;
    const int lrA = w * (BM / 4);
    const int lrB = w * (BN / 4);

    // per-lane global source offsets for staging
    long long ga0, ga1 = 0;
    {
        int am0 = m0 + lrA + srow;
        int am1 = am0 + 16;
        long long r0, r1;
        if (AMODE == 0) { r0 = am0; r1 = am1; }
        else if (AMODE == 1) {
            r0 = glist[off + ((am0 < cnt) ? am0 : 0)];
            r1 = A2 ? glist[off + ((am1 < cnt) ? am1 : 0)] : 0;
        } else {
            r0 = off + ((am0 < cnt) ? am0 : 0);
            r1 = A2 ? (off + ((am1 < cnt) ? am1 : 0)) : 0;
        }
        ga0 = r0 * lda + schk;
        if (A2) ga1 = r1 * lda + schk;
    }
    const long long gb0 = (long long)(n0 + lrB + srow) * ldb + schk;
    const long long gb1 = gb0 + 16LL * ldb;

    auto stage = [&](int bf, int k0) {
        #pragma unroll
        for (int u = 0; u < KU; ++u) {
            const int ko = k0 + u * 32;
            GL16(Ah + ga0 + ko, &AHs[bf][u][lrA][0]);
            if constexpr (A2) GL16(Ah + ga1 + ko, &AHs[bf][u][lrA + 16][0]);
            if constexpr (TERMS >= 2) {
                GL16(Al + ga0 + ko, &ALs[bf][u][lrA][0]);
                if constexpr (A2) GL16(Al + ga1 + ko, &ALs[bf][u][lrA + 16][0]);
            }
            GL16(Bh + gb0 + ko, &BHs[bf][u][lrB][0]);
            if constexpr (B2) GL16(Bh + gb1 + ko, &BHs[bf][u][lrB + 16][0]);
            if constexpr (TERMS >= 3) {
                GL16(Bl + gb0 + ko, &BLs[bf][u][lrB][0]);
                if constexpr (B2) GL16(Bl + gb1 + ko, &BLs[bf][u][lrB + 16][0]);
            }
        }
    };

    f32x4 acc[MI][4];
    #pragma unroll
    for (int i = 0; i < MI; ++i)
        #pragma unroll
        for (int j = 0; j < 4; ++j) acc[i][j] = f32x4{0.f, 0.f, 0.f, 0.f};

    const int nk = K / (32 * KU);
    int cur = 0;
    stage(0, 0);
    __syncthreads();
    for (int t = 0; t < nk; ++t) {
        if (t + 1 < nk) stage(cur ^ 1, (t + 1) * 32 * KU);
        #pragma unroll
        for (int u = 0; u < KU; ++u) {
            s16x8 ah[MI], al[MI], bh[4], bl[4];
            #pragma unroll
            for (int i = 0; i < MI; ++i)
                ah[i] = *(const s16x8*)&AHs[cur][u][wmB + i * 16 + l16][grp * 8];
            if constexpr (TERMS >= 2) {
                #pragma unroll
                for (int i = 0; i < MI; ++i)
                    al[i] = *(const s16x8*)&ALs[cur][u][wmB + i * 16 + l16][grp * 8];
            }
            #pragma unroll
            for (int j = 0; j < 4; ++j)
                bh[j] = *(const s16x8*)&BHs[cur][u][wnB + j * 16 + l16][grp * 8];
            if constexpr (TERMS >= 3) {
                #pragma unroll
                for (int j = 0; j < 4; ++j)
                    bl[j] = *(const s16x8*)&BLs[cur][u][wnB + j * 16 + l16][grp * 8];
            }
            #pragma unroll
            for (int i = 0; i < MI; ++i) {
                #pragma unroll
                for (int j = 0; j < 4; ++j) {
                    acc[i][j] = mfma16(ah[i], bh[j], acc[i][j]);
                    if constexpr (TERMS >= 3) acc[i][j] = mfma16(ah[i], bl[j], acc[i][j]);
                    if constexpr (TERMS >= 2) acc[i][j] = mfma16(al[i], bh[j], acc[i][j]);
                }
            }
        }
        __syncthreads();
        cur ^= 1;
    }
    // ---- epilogue ----
    #pragma unroll
    for (int i = 0; i < MI; ++i) {
        #pragma unroll
        for (int j = 0; j < 4; ++j) {
            int col = n0 + wnB + j * 16 + l16;
            #pragma unroll
            for (int r = 0; r < 4; ++r) {
                int mr = m0 + wmB + i * 16 + grp * 4 + r;
                if (AMODE != 0 && mr >= cnt) continue;
                long long crow = (AMODE == 0) ? mr : (off + mr);
                float val = acc[i][j][r];
                if (EPI == 0) {
                    ((float*)Cv)[crow * ldc + col] = val;
                } else if (EPI == 1) {
                    ((float*)Cv)[crow * ldc + col] = val + RES[crow * ldc + col];
                } else if (EPI == 2) {
                    ((u16*)Cv)[crow * ldc + col] = f2b(gelu_t(val));
                } else if (EPI == 5) {
                    ((u16*)Cv)[crow * ldc + col] = f2b(val);
                } else {
                    float v2 = val + RES[crow * ldc + col];
                    ((float*)Cv)[crow * ldc + col] = v2;
                    C2[crow * ldc + col] = v2;
                }
            }
        }
    }
}

// -------- K/V prep: K split bf16 (row layout), V^T split bf16 --------
__global__ __launch_bounds__(256) void kvprep(const float* __restrict__ qkvf,
    u16* __restrict__ kTh, u16* __restrict__ kTl,
    u16* __restrict__ vTh, u16* __restrict__ vTl)
{
    __shared__ float tile[64][68];
    const int st = blockIdx.x * 64;
    const int b = blockIdx.y & 1, kvh = blockIdx.y >> 1;
    const int tid = threadIdx.x;
    #pragma unroll
    for (int h = 0; h < 4; ++h) {
        int c = tid + h * 256;
        int srow = c >> 4, dseg = c & 15;
        f32x4 v = *(const f32x4*)(qkvf + (size_t)((st + srow) * BATCH + b) * QKVO
                                  + (NHEAD + NKVH) * HDIM + kvh * HDIM + dseg * 4);
        *(f32x4*)&tile[srow][dseg * 4] = v;
    }
    {
        int row = tid >> 2, qseg = tid & 3;
        const float* kr = qkvf + (size_t)((st + row) * BATCH + b) * QKVO
                          + NHEAD * HDIM + kvh * HDIM + qseg * 16;
        size_t ko = ((size_t)((b * NKVH + kvh) * SEQ + st + row)) * HDIM + qseg * 16;
        #pragma unroll
        for (int c = 0; c < 4; ++c) {
            f32x4 x = *(const f32x4*)(kr + c * 4);
            s16x4 vh, vl;
            #pragma unroll
            for (int j = 0; j < 4; ++j) {
                u16 hb, lb; split2(x[j], hb, lb);
                vh[j] = (short)hb; vl[j] = (short)lb;
            }
            *(s16x4*)(kTh + ko + c * 4) = vh;
            *(s16x4*)(kTl + ko + c * 4) = vl;
        }
    }
    __syncthreads();
    #pragma unroll
    for (int h = 0; h < 2; ++h) {
        int c = tid + h * 256;
        int drow = c >> 3, sseg = c & 7;
        s16x8 vh, vl;
        #pragma unroll
        for (int j = 0; j < 8; ++j) {
            u16 hb, lb; split2(tile[sseg * 8 + j][drow], hb, lb);
            vh[j] = (short)hb; vl[j] = (short)lb;
        }
        size_t oo = ((size_t)((b * NKVH + kvh) * HDIM + drow)) * SEQ + st + sseg * 8;
        *(s16x8*)(vTh + oo) = vh;
        *(s16x8*)(vTl + oo) = vl;
    }
}

// --- Flash attention partials: 1 wave, 32 q-rows, 128-row kv chunk ---
__global__ __launch_bounds__(64, 3) void attn_part(
    const float* __restrict__ qkvf,
    const u16* __restrict__ kTh, const u16* __restrict__ kTl,
    const u16* __restrict__ vTh, const u16* __restrict__ vTl,
    float* __restrict__ part)
{
    __shared__ u16 plh[32][40];
    __shared__ u16 pll[32][40];
    const int p = blockIdx.x;
    int qt, c;
    if (p < 32)       { c = 0; qt = p; }
    else if (p < 60)  { c = 1; qt = p - 28; }
    else if (p < 84)  { c = 2; qt = p - 52; }
    else if (p < 104) { c = 3; qt = p - 72; }
    else if (p < 120) { c = 4; qt = p - 88; }
    else if (p < 132) { c = 5; qt = p - 100; }
    else if (p < 140) { c = 6; qt = p - 108; }
    else              { c = 7; qt = p - 112; }
    const int h = blockIdx.y, b = blockIdx.z;
    const int kvh = h >> 2;
    const int lane = threadIdx.x, l16 = lane & 15, grp = lane >> 4;

    s16x8 qh[2][2], ql[2][2];
    #pragma unroll
    for (int mt = 0; mt < 2; ++mt) {
        const float* qb = qkvf + (size_t)((qt * 32 + mt * 16 + l16) * BATCH + b) * QKVO
                          + h * HDIM + grp * 8;
        #pragma unroll
        for (int ks = 0; ks < 2; ++ks) {
            #pragma unroll
            for (int j = 0; j < 8; ++j) {
                u16 hb, lb; split2(qb[ks * 32 + j], hb, lb);
                qh[mt][ks][j] = (short)hb; ql[mt][ks][j] = (short)lb;
            }
        }
    }
    float mrow[2][4], lsum[2][4];
    f32x4 o[2][4];
    #pragma unroll
    for (int mt = 0; mt < 2; ++mt) {
        #pragma unroll
        for (int r = 0; r < 4; ++r) { mrow[mt][r] = -__builtin_inff(); lsum[mt][r] = 0.f; }
        #pragma unroll
        for (int db = 0; db < 4; ++db) o[mt][db] = f32x4{0.f, 0.f, 0.f, 0.f};
    }

    const size_t kvbase = (size_t)(b * NKVH + kvh) * SEQ;
    const int kv0 = c * 128;
    const int kv_hi = min(kv0 + 128, qt * 32 + 32);
    const int nt = (kv_hi - kv0 + 31) >> 5;
    for (int jb = 0; jb < nt; ++jb) {
        const int kvb = kv0 + jb * 32;
        f32x4 s[2][2];
        #pragma unroll
        for (int t2 = 0; t2 < 2; ++t2) {
            size_t kb = (kvbase + kvb + t2 * 16 + l16) * HDIM + grp * 8;
            f32x4 z0 = f32x4{0.f, 0.f, 0.f, 0.f};
            f32x4 z1 = f32x4{0.f, 0.f, 0.f, 0.f};
            #pragma unroll
            for (int ks = 0; ks < 2; ++ks) {
                s16x8 kh = *(const s16x8*)(kTh + kb + ks * 32);
                s16x8 kl = *(const s16x8*)(kTl + kb + ks * 32);
                z0 = mfma16(qh[0][ks], kh, z0);
                z0 = mfma16(qh[0][ks], kl, z0);
                z0 = mfma16(ql[0][ks], kh, z0);
                z1 = mfma16(qh[1][ks], kh, z1);
                z1 = mfma16(qh[1][ks], kl, z1);
                z1 = mfma16(ql[1][ks], kh, z1);
            }
            s[0][t2] = z0; s[1][t2] = z1;
        }
        #pragma unroll
        for (int mt = 0; mt < 2; ++mt) {
            #pragma unroll
            for (int r = 0; r < 4; ++r) {
                const int qrow = qt * 32 + mt * 16 + grp * 4 + r;
                float a0 = s[mt][0][r] * 0.125f; if (kvb + l16 > qrow) a0 = -__builtin_inff();
                float a1 = s[mt][1][r] * 0.125f; if (kvb + 16 + l16 > qrow) a1 = -__builtin_inff();
                float mx = fmaxf(a0, a1);
                #pragma unroll
                for (int t = 1; t < 16; t <<= 1) mx = fmaxf(mx, __shfl_xor(mx, t));
                float mn = fmaxf(mrow[mt][r], mx);
                float sc = __expf(mrow[mt][r] - mn);
                float p0 = __expf(a0 - mn), p1 = __expf(a1 - mn);
                float ps = p0 + p1;
                #pragma unroll
                for (int t = 1; t < 16; t <<= 1) ps += __shfl_xor(ps, t);
                lsum[mt][r] = lsum[mt][r] * sc + ps;
                mrow[mt][r] = mn;
                s[mt][0][r] = p0; s[mt][1][r] = p1;
                #pragma unroll
                for (int db = 0; db < 4; ++db) o[mt][db][r] *= sc;
            }
        }
        __syncthreads();
        #pragma unroll
        for (int mt = 0; mt < 2; ++mt) {
            #pragma unroll
            for (int t2 = 0; t2 < 2; ++t2) {
                #pragma unroll
                for (int r = 0; r < 4; ++r) {
                    u16 hb, lb; split2(s[mt][t2][r], hb, lb);
                    plh[mt * 16 + grp * 4 + r][t2 * 16 + l16] = hb;
                    pll[mt * 16 + grp * 4 + r][t2 * 16 + l16] = lb;
                }
            }
        }
        __syncthreads();
        s16x8 pah0 = *(const s16x8*)&plh[l16][grp * 8];
        s16x8 pal0 = *(const s16x8*)&pll[l16][grp * 8];
        s16x8 pah1 = *(const s16x8*)&plh[16 + l16][grp * 8];
        s16x8 pal1 = *(const s16x8*)&pll[16 + l16][grp * 8];
        #pragma unroll
        for (int db = 0; db < 4; ++db) {
            size_t vo = ((size_t)((b * NKVH + kvh) * HDIM + db * 16 + l16)) * SEQ + kvb + grp * 8;
            s16x8 vh = *(const s16x8*)(vTh + vo);
            s16x8 vl = *(const s16x8*)(vTl + vo);
            o[0][db] = mfma16(pah0, vh, o[0][db]);
            o[0][db] = mfma16(pah0, vl, o[0][db]);
            o[0][db] = mfma16(pal0, vh, o[0][db]);
            o[1][db] = mfma16(pah1, vh, o[1][db]);
            o[1][db] = mfma16(pah1, vl, o[1][db]);
            o[1][db] = mfma16(pal1, vh, o[1][db]);
        }
    }
    float* rec = part + (((size_t)(b * NHEAD + h) * NPART + p) * PREC);
    #pragma unroll
    for (int mt = 0; mt < 2; ++mt) {
        #pragma unroll
        for (int db = 0; db < 4; ++db) {
            #pragma unroll
            for (int r = 0; r < 4; ++r)
                rec[(mt * 16 + grp * 4 + r) * 64 + db * 16 + l16] = o[mt][db][r];
        }
    }
    if (l16 == 0) {
        #pragma unroll
        for (int mt = 0; mt < 2; ++mt) {
            #pragma unroll
            for (int r = 0; r < 4; ++r) {
                rec[2048 + mt * 16 + grp * 4 + r] = mrow[mt][r];
                rec[2080 + mt * 16 + grp * 4 + r] = lsum[mt][r];
            }
        }
    }
}

// ------- combine partials -> split-bf16 attention output -------------
__global__ __launch_bounds__(256) void attn_comb(const float* __restrict__ part,
    u16* __restrict__ attn_h, u16* __restrict__ attn_l)
{
    const int qt16 = blockIdx.x, h = blockIdx.y, b = blockIdx.z;
    const int qt32 = qt16 >> 1;
    const int lrow = (qt16 & 1) * 16 + (threadIdx.x >> 4);
    const int nch = (qt32 >> 2) + 1;
    const int c4 = (threadIdx.x & 15) * 4;
    const size_t base = (size_t)(b * NHEAD + h) * NPART;
    const int pbase[8] = {0, 28, 52, 72, 88, 100, 108, 112};  // p = pbase[c] + qt32
    float mv[8], lv[8];
    float M = -__builtin_inff();
    #pragma unroll
    for (int c = 0; c < 8; ++c) {
        if (c < nch) {
            const float* rec = part + (base + pbase[c] + qt32) * PREC;
            mv[c] = rec[2048 + lrow];
            lv[c] = rec[2080 + lrow];
            M = fmaxf(M, mv[c]);
        }
    }
    float L = 0.f;
    f32x4 acc = f32x4{0.f, 0.f, 0.f, 0.f};
    #pragma unroll
    for (int c = 0; c < 8; ++c) {
        if (c < nch) {
            const float* rec = part + (base + pbase[c] + qt32) * PREC;
            float wgt = __expf(mv[c] - M);
            L += lv[c] * wgt;
            f32x4 ov = *(const f32x4*)(rec + lrow * 64 + c4);
            acc[0] += ov[0] * wgt; acc[1] += ov[1] * wgt;
            acc[2] += ov[2] * wgt; acc[3] += ov[3] * wgt;
        }
    }
    float inv = 1.f / L;
    const int qrow = qt32 * 32 + lrow;
    size_t oo = (size_t)(qrow * BATCH + b) * HID + h * HDIM + c4;
    #pragma unroll
    for (int j = 0; j < 4; ++j) {
        u16 hb, lb; split2(acc[j] * inv, hb, lb);
        attn_h[oo + j] = hb;
        attn_l[oo + j] = lb;
    }
}

// ---------------- Router: logits, softmax, top2, counts --------------
__global__ __launch_bounds__(64) void router_k(const float* __restrict__ ln2,
    const float* __restrict__ rw, int* __restrict__ e01, float* __restrict__ p01,
    int* __restrict__ cnt)
{
    const int t = blockIdx.x, lane = threadIdx.x;
    const float* xr = ln2 + (size_t)t * HID + lane * 16;
    float x[16];
    #pragma unroll
    for (int c = 0; c < 4; ++c) {
        f32x4 u = *(const f32x4*)(xr + c * 4);
        #pragma unroll
        for (int j = 0; j < 4; ++j) x[c * 4 + j] = u[j];
    }
    float lg[8];
    #pragma unroll
    for (int e = 0; e < 8; ++e) {
        const float* wr = rw + (size_t)e * HID + lane * 16;
        float a = 0.f;
        #pragma unroll
        for (int c = 0; c < 4; ++c) {
            f32x4 wv = *(const f32x4*)(wr + c * 4);
            #pragma unroll
            for (int j = 0; j < 4; ++j) a += x[c * 4 + j] * wv[j];
        }
        #pragma unroll
        for (int off = 32; off >= 1; off >>= 1) a += __shfl_xor(a, off);
        lg[e] = a;
    }
    float mx = lg[0];
    #pragma unroll
    for (int e = 1; e < 8; ++e) mx = fmaxf(mx, lg[e]);
    float pe[8], ssum = 0.f;
    #pragma unroll
    for (int e = 0; e < 8; ++e) { pe[e] = expf(lg[e] - mx); ssum += pe[e]; }
    float inv = 1.f / ssum;
    int e0 = 0; float b0 = -1.f;
    #pragma unroll
    for (int e = 0; e < 8; ++e) { float p = pe[e] * inv; if (p > b0) { b0 = p; e0 = e; } }
    int e1 = -1; float b1 = -1.f;
    #pragma unroll
    for (int e = 0; e < 8; ++e) {
        if (e == e0) continue;
        float p = pe[e] * inv; if (p > b1) { b1 = p; e1 = e; }
    }
    if (lane == 0) {
        e01[2 * t] = e0; e01[2 * t + 1] = e1;
        p01[2 * t] = b0; p01[2 * t + 1] = b1;
        atomicAdd(&cnt[e0], 1); atomicAdd(&cnt[e1], 1);
    }
}

__global__ void init_k(int* cnt) {
    int i = threadIdx.x;
    if (i < 8) cnt[i] = 0;
}
__global__ void scan_k(const int* cnt, int* offs) {
    if (threadIdx.x == 0 && blockIdx.x == 0) {
        int a = 0;
        for (int e = 0; e < 8; ++e) { offs[e] = a; a += cnt[e]; }
    }
}
__global__ __launch_bounds__(64) void scatter_det(const int* __restrict__ e01,
    const float* __restrict__ p01, const int* __restrict__ offs,
    int* __restrict__ tok_of, float* __restrict__ slot_p, int* __restrict__ slot_of)
{
    const int e = blockIdx.x;
    const int lane = threadIdx.x;
    int base = offs[e];
    for (int c = 0; c < TOK; c += 64) {
        int t = c + lane;
        int kk = -1;
        if (e01[2 * t] == e) kk = 0;
        else if (e01[2 * t + 1] == e) kk = 1;
        int f = (kk >= 0) ? 1 : 0;
        int sc = f;
        #pragma unroll
        for (int o = 1; o < 64; o <<= 1) {
            int nn = __shfl_up(sc, o);
            if (lane >= o) sc += nn;
        }
        if (kk >= 0) {
            int slot = base + sc - 1;
            tok_of[slot] = t;
            slot_p[slot] = p01[2 * t + kk];
            slot_of[2 * t + kk] = slot;
        }
        base += __shfl(sc, 63);
    }
}

// ---- final MoE combine: out[t] += p0*y[s0] + p1*y[s1] (y bf16) ------
__global__ __launch_bounds__(256) void moe_comb(const u16* __restrict__ yb,
    const int* __restrict__ slot_of, const float* __restrict__ p01,
    float* __restrict__ out)
{
    const int t = blockIdx.x;
    const int c4 = threadIdx.x * 4;
    const int s0 = slot_of[2 * t], s1 = slot_of[2 * t + 1];
    const float p0 = p01[2 * t], p1 = p01[2 * t + 1];
    s16x4 y0 = *(const s16x4*)(yb + (size_t)s0 * HID + c4);
    s16x4 y1 = *(const s16x4*)(yb + (size_t)s1 * HID + c4);
    f32x4 o = *(f32x4*)(out + (size_t)t * HID + c4);
    #pragma unroll
    for (int j = 0; j < 4; ++j)
        o[j] += p0 * b2f((u16)y0[j]) + p1 * b2f((u16)y1[j]);
    *(f32x4*)(out + (size_t)t * HID + c4) = o;
}

__global__ void sentinel_k(float* out) {
    out[blockIdx.x * 256 + threadIdx.x] = 12345.0f;
}

extern "C" void kernel_launch(void* const* d_in, const int* in_sizes, int n_in,
                              void* d_out, int out_size, void* d_ws, size_t ws_size,
                              hipStream_t stream)
{
    (void)in_sizes; (void)n_in; (void)out_size;
    const float* hs    = (const float*)d_in[0];
    const float* ln1w  = (const float*)d_in[1];
    const float* ln1b  = (const float*)d_in[2];
    const float* ln2w  = (const float*)d_in[3];
    const float* ln2b  = (const float*)d_in[4];
    const float* qkvw  = (const float*)d_in[5];
    const float* projw = (const float*)d_in[6];
    const float* rw    = (const float*)d_in[7];
    const float* w1    = (const float*)d_in[8];
    const float* w2    = (const float*)d_in[9];
    float* out = (float*)d_out;
    char* ws = (char*)d_ws;

    size_t o = 0;
    auto alloc = [&](size_t bytes) -> void* {
        void* p = ws + o; o += (bytes + 255) & ~(size_t)255; return p;
    };
    u16*   w1t    = (u16*)alloc((size_t)NEXP * FFN * HID * 2);   // [E][F][H]; early: partials
    u16*   w2t    = (u16*)alloc((size_t)NEXP * HID * FFN * 2);   // [E][H][F]; partials overflow here too
    u16*   qkvwh  = (u16*)alloc((size_t)QKVO * HID * 2);
    u16*   qkvwl  = (u16*)alloc((size_t)QKVO * HID * 2);
    u16*   projwh = (u16*)alloc((size_t)HID * HID * 2);
    u16*   projwl = (u16*)alloc((size_t)HID * HID * 2);
    u16*   ln1h   = (u16*)alloc((size_t)TOK * HID * 2);          // also attnh
    u16*   ln1l   = (u16*)alloc((size_t)TOK * HID * 2);          // also attnl
    float* qkvf   = (float*)alloc((size_t)TOK * QKVO * 4);       // also ln2f, then yb
    u16*   kTh    = (u16*)alloc((size_t)BATCH * NKVH * SEQ * HDIM * 2);
    u16*   kTl    = (u16*)alloc((size_t)BATCH * NKVH * SEQ * HDIM * 2);
    u16*   vTh    = (u16*)alloc((size_t)BATCH * NKVH * HDIM * SEQ * 2);
    u16*   vTl    = (u16*)alloc((size_t)BATCH * NKVH * HDIM * SEQ * 2);
    float* haf    = (float*)alloc((size_t)TOK * HID * 4);
    u16*   ln2h   = (u16*)alloc((size_t)TOK * HID * 2);
    u16*   a1b    = (u16*)alloc((size_t)TOK * 2 * FFN * 2);
    int*   e01    = (int*)alloc(TOK * 2 * 4);
    float* p01    = (float*)alloc(TOK * 2 * 4);
    int*   cnt    = (int*)alloc(256);
    int*   offs   = (int*)alloc(256);
    int*   tok_of = (int*)alloc(TOK * 2 * 4);
    float* slot_p = (float*)alloc(TOK * 2 * 4);
    int*   slot_of = (int*)alloc(TOK * 2 * 4);
    size_t need = o;

    if (ws_size < need) {
        sentinel_k<<<TOK * HID / 256, 256, 0, stream>>>(out);
        return;
    }

    u16* attnh = ln1h;
    u16* attnl = ln1l;
    float* ln2f = qkvf;
    u16*  yb = (u16*)qkvf;       // 8.4MB, region dead after router_k
    float* part = (float*)w1t;   // 38.9 MB partials; spans w1t+w2t, both written later

    // weight prep needed before attention
    split_cast_k<<<QKVO * HID / 4 / 256, 256, 0, stream>>>(qkvw, qkvwh, qkvwl);
    split_cast_k<<<HID * HID / 4 / 256, 256, 0, stream>>>(projw, projwh, projwl);
    // LN1 -> split hi/lo
    ln_k<2><<<TOK, 256, 0, stream>>>(hs, ln1w, ln1b, nullptr, ln1h, ln1l);
    // QKV (3-term, 64x64 tile -> 768 blocks, KU=1)
    gemm_db<0, 3, 0, 2, 1><<<dim3(QKVO / 64, TOK / 64, 1), 256, 0, stream>>>(
        ln1h, ln1l, qkvwh, qkvwl, qkvf, nullptr, nullptr, nullptr, nullptr, nullptr, nullptr,
        TOK, QKVO, HID, HID, HID, QKVO, 0);
    kvprep<<<dim3(SEQ / 64, BATCH * NKVH), 256, 0, stream>>>(qkvf, kTh, kTl, vTh, vTl);
    // split-KV flash attention: 32 q-rows per wave, 128-row kv chunks
    attn_part<<<dim3(NPART, NHEAD, BATCH), 64, 0, stream>>>(
        qkvf, kTh, kTl, vTh, vTl, part);
    attn_comb<<<dim3(SEQ / 16, NHEAD, BATCH), 256, 0, stream>>>(part, attnh, attnl);
    // proj + residual -> haf AND out (3-term, 64x64 tile, KU=1 -> 32KB LDS)
    gemm_db<0, 3, 4, 2, 1><<<dim3(HID / 64, TOK / 64, 1), 256, 0, stream>>>(
        attnh, attnl, projwh, projwl, haf, hs, out, nullptr, nullptr, nullptr, nullptr,
        TOK, HID, HID, HID, HID, HID, 0);
    // LN2 -> f32 (router) + hi only (FC1 is 1-term)
    ln_k<4><<<TOK, 256, 0, stream>>>(haf, ln2w, ln2b, ln2f, ln2h, nullptr);
    // MoE weight prep (after partials are dead)
    trans_cast_k<<<dim3(FFN / 64, HID / 64, NEXP), 256, 0, stream>>>(w1, w1t, HID, FFN);
    trans_cast_k<<<dim3(HID / 64, FFN / 64, NEXP), 256, 0, stream>>>(w2, w2t, FFN, HID);
    // router + deterministic bucketing
    init_k<<<1, 64, 0, stream>>>(cnt);
    router_k<<<TOK, 64, 0, stream>>>(ln2f, rw, e01, p01, cnt);
    scan_k<<<1, 1, 0, stream>>>(cnt, offs);
    scatter_det<<<NEXP, 64, 0, stream>>>(e01, p01, offs, tok_of, slot_p, slot_of);
    // FC1 (1-term, gather rows, gelu->bf16, 128x64 tile, KU=2 -> 48KB LDS)
    gemm_db<1, 1, 2, 1, 2><<<dim3(FFN / 64, TOK / 128, NEXP), 256, 0, stream>>>(
        ln2h, nullptr, w1t, nullptr, a1b, nullptr, nullptr, tok_of, offs, cnt, nullptr,
        0, FFN, HID, HID, HID, FFN, (long long)FFN * HID);
    // FC2 (1-term, contig rows, bf16 y store, 128x64 tile, KU=2 -> 48KB LDS)
    gemm_db<2, 1, 5, 1, 2><<<dim3(HID / 64, TOK / 128, NEXP), 256, 0, stream>>>(
        a1b, nullptr, w2t, nullptr, yb, nullptr, nullptr, tok_of, offs, cnt, slot_p,
        0, HID, FFN, FFN, FFN, HID, (long long)HID * FFN);
    // final combine: out += p0*y0 + p1*y1
    moe_comb<<<TOK, 256, 0, stream>>>(yb, slot_of, p01, out);
}

// Round 15
// 326.170 us; speedup vs baseline: 1.0870x; 1.0870x over previous
//
#include <hip/hip_runtime.h>
#include <hip/hip_bf16.h>

typedef unsigned short u16;
typedef __attribute__((ext_vector_type(8))) short s16x8;
typedef __attribute__((ext_vector_type(4))) short s16x4;
typedef __attribute__((ext_vector_type(4))) float f32x4;

#define SEQ 1024
#define BATCH 2
#define HID 1024
#define NHEAD 16
#define NKVH 4
#define HDIM 64
#define NEXP 8
#define FFN 2048
#define TOK (SEQ*BATCH)
#define QKVO ((NHEAD + 2*NKVH)*HDIM)   // 1536
#define NPART 80                        // 32-row q-tiles, 256-row kv chunks
#define PREC 2112                       // 32*64 o + 32 m + 32 l

// async global->LDS, 16B per lane, dest = uniform base + lane*16
#define GL16(gp, lp) __builtin_amdgcn_global_load_lds( \
    (const __attribute__((address_space(1))) unsigned int*)(gp), \
    (__attribute__((address_space(3))) unsigned int*)(lp), 16, 0, 0)

__device__ __forceinline__ float b2f(u16 u) {
    unsigned int x = ((unsigned int)u) << 16;
    return __uint_as_float(x);
}
__device__ __forceinline__ u16 f2b(float f) {
    unsigned int x = __float_as_uint(f);
    x = (x + 0x7FFFu + ((x >> 16) & 1u)) >> 16;
    return (u16)x;
}
__device__ __forceinline__ void split2(float x, u16& hi, u16& lo) {
    hi = f2b(x);
    lo = f2b(x - b2f(hi));
}
__device__ __forceinline__ f32x4 mfma16(s16x8 a, s16x8 b, f32x4 c) {
    return __builtin_amdgcn_mfma_f32_16x16x32_bf16(a, b, c, 0, 0, 0);
}
__device__ __forceinline__ float gelu_t(float x) {
    float x3 = x * x * x;
    return 0.5f * x * (1.0f + tanhf(0.7978845608028654f * (x + 0.044715f * x3)));
}

// ------- LayerNorm: f32 in; OUTMODE: 0=f32, 2=hi/lo, 3=f32+hi/lo, 4=f32+hi -
template<int OUTMODE>
__global__ __launch_bounds__(256) void ln_k(const float* __restrict__ xin,
    const float* __restrict__ wgt, const float* __restrict__ bia,
    float* __restrict__ outf, u16* __restrict__ outh, u16* __restrict__ outl)
{
    __shared__ float red[8];
    const int t = blockIdx.x, tid = threadIdx.x;
    f32x4 u = *((const f32x4*)(xin + (size_t)t * HID) + tid);
    float s = u[0] + u[1] + u[2] + u[3];
    #pragma unroll
    for (int off = 32; off >= 1; off >>= 1) s += __shfl_xor(s, off);
    if ((tid & 63) == 0) red[tid >> 6] = s;
    __syncthreads();
    float mu = (red[0] + red[1] + red[2] + red[3]) * (1.0f / HID);
    float d0 = u[0]-mu, d1 = u[1]-mu, d2 = u[2]-mu, d3 = u[3]-mu;
    float ss = d0*d0 + d1*d1 + d2*d2 + d3*d3;
    #pragma unroll
    for (int off = 32; off >= 1; off >>= 1) ss += __shfl_xor(ss, off);
    if ((tid & 63) == 0) red[4 + (tid >> 6)] = ss;
    __syncthreads();
    float var = (red[4] + red[5] + red[6] + red[7]) * (1.0f / HID);
    float rs = 1.0f / sqrtf(var + 1e-5f);
    f32x4 wv = *((const f32x4*)wgt + tid);
    f32x4 bv = *((const f32x4*)bia + tid);
    f32x4 o;
    o[0] = d0*rs*wv[0] + bv[0];
    o[1] = d1*rs*wv[1] + bv[1];
    o[2] = d2*rs*wv[2] + bv[2];
    o[3] = d3*rs*wv[3] + bv[3];
    if (OUTMODE == 0 || OUTMODE >= 3)
        *((f32x4*)(outf + (size_t)t * HID) + tid) = o;
    if (OUTMODE == 2 || OUTMODE == 3) {
        s16x4 h, l;
        #pragma unroll
        for (int j = 0; j < 4; ++j) {
            u16 hb, lb; split2(o[j], hb, lb);
            h[j] = (short)hb; l[j] = (short)lb;
        }
        *((s16x4*)(outh + (size_t)t * HID) + tid) = h;
        *((s16x4*)(outl + (size_t)t * HID) + tid) = l;
    }
    if (OUTMODE == 4) {
        s16x4 h;
        #pragma unroll
        for (int j = 0; j < 4; ++j) h[j] = (short)f2b(o[j]);
        *((s16x4*)(outh + (size_t)t * HID) + tid) = h;
    }
}

// -------- weight prep: split-cast f32 -> bf16 hi/lo (same layout) ----
__global__ __launch_bounds__(256) void split_cast_k(const float* __restrict__ in,
    u16* __restrict__ hi, u16* __restrict__ lo)
{
    int i = blockIdx.x * 256 + threadIdx.x;
    f32x4 v = ((const f32x4*)in)[i];
    s16x4 h, l;
    #pragma unroll
    for (int j = 0; j < 4; ++j) {
        u16 hb, lb; split2(v[j], hb, lb);
        h[j] = (short)hb; l[j] = (short)lb;
    }
    ((s16x4*)hi)[i] = h;
    ((s16x4*)lo)[i] = l;
}

// -------- weight prep: transpose-cast f32 [E][R][C] -> bf16 [E][C][R]
__global__ __launch_bounds__(256) void trans_cast_k(const float* __restrict__ in,
    u16* __restrict__ out, int R, int C)
{
    __shared__ float tile[64][65];
    const int e = blockIdx.z;
    const float* src = in + (size_t)e * R * C;
    u16* dst = out + (size_t)e * C * R;
    const int r0 = blockIdx.y * 64, c0 = blockIdx.x * 64;
    const int tr = threadIdx.x >> 2, tc = (threadIdx.x & 3) * 16;
    #pragma unroll
    for (int j = 0; j < 4; ++j) {
        f32x4 v = *(const f32x4*)(src + (size_t)(r0 + tr) * C + c0 + tc + j * 4);
        *(f32x4*)&tile[tr][tc + j * 4] = v;
    }
    __syncthreads();
    s16x8 o0, o1;
    #pragma unroll
    for (int j = 0; j < 8; ++j) o0[j] = (short)f2b(tile[tc + j][tr]);
    #pragma unroll
    for (int j = 0; j < 8; ++j) o1[j] = (short)f2b(tile[tc + 8 + j][tr]);
    u16* dp = dst + (size_t)(c0 + tr) * R + r0 + tc;
    *(s16x8*)dp = o0;
    *(s16x8*)(dp + 8) = o1;
}

// ------ gemm_db: bf16 MFMA GEMM, global_load_lds + double buffer -----
// TERMS: 1 = AhBh ; 2 = + AlBh ; 3 = + AhBl
// AMODE: 0 plain rows; 1 gather rows glist[off+r]; 2 contiguous off+r
// EPI: 0 f32; 1 f32+RES; 2 bf16(gelu); 4 f32+RES dual; 5 bf16 plain
// TILE: 0 = 128x128; 1 = 128x64; 2 = 64x64
// KU: K-chunks (x32) staged per barrier iteration
template<int AMODE, int TERMS, int EPI, int TILE, int KU>
__global__ __launch_bounds__(256, 2) void gemm_db(
    const u16* __restrict__ Ah, const u16* __restrict__ Al,
    const u16* __restrict__ Bh, const u16* __restrict__ Bl,
    void* __restrict__ Cv, const float* __restrict__ RES, float* __restrict__ C2,
    const int* __restrict__ glist, const int* __restrict__ offs,
    const int* __restrict__ cnts, const float* __restrict__ slot_p,
    int M, int N, int K, int lda, int ldb, int ldc, long long bStrideE)
{
    constexpr int BM = (TILE == 2) ? 64 : 128;
    constexpr int BN = (TILE == 0) ? 128 : 64;
    constexpr int MI = (TILE == 0) ? 4 : ((TILE == 1) ? 2 : 1);
    constexpr bool A2 = (BM == 128);
    constexpr bool B2 = (BN == 128);
    __shared__ u16 AHs[2][KU][BM][32];
    __shared__ u16 ALs[(TERMS >= 2) ? 2 : 1][(TERMS >= 2) ? KU : 1][(TERMS >= 2) ? BM : 1][32];
    __shared__ u16 BHs[2][KU][BN][32];
    __shared__ u16 BLs[(TERMS >= 3) ? 2 : 1][(TERMS >= 3) ? KU : 1][(TERMS >= 3) ? BN : 1][32];

    const int tid = threadIdx.x;
    const int m0 = blockIdx.y * BM;
    const int n0 = blockIdx.x * BN;
    int off = 0, cnt = M;
    if (AMODE != 0) {
        const int e = blockIdx.z;
        off = offs[e]; cnt = cnts[e];
        if (m0 >= cnt) return;
        long long be = (long long)e * bStrideE;
        Bh += be;
        if (TERMS >= 3) Bl += be;
    }
    const int lane = tid & 63, w = tid >> 6;
    const int wmB = (TILE == 0) ? ((w >> 1) * 64) : (w * (BM / 4));
    const int wnB = (TILE == 0) ? ((w & 1) * 64) : 0;
    const int l16 = lane & 15, grp = lane >> 4;
    const int srow = lane >> 2, schk = (lane & 3) * 8;
    const int lrA = w * (BM / 4);
    const int lrB = w * (BN / 4);

    long long ga0, ga1 = 0;
    {
        int am0 = m0 + lrA + srow;
        int am1 = am0 + 16;
        long long r0, r1;
        if (AMODE == 0) { r0 = am0; r1 = am1; }
        else if (AMODE == 1) {
            r0 = glist[off + ((am0 < cnt) ? am0 : 0)];
            r1 = A2 ? glist[off + ((am1 < cnt) ? am1 : 0)] : 0;
        } else {
            r0 = off + ((am0 < cnt) ? am0 : 0);
            r1 = A2 ? (off + ((am1 < cnt) ? am1 : 0)) : 0;
        }
        ga0 = r0 * lda + schk;
        if (A2) ga1 = r1 * lda + schk;
    }
    const long long gb0 = (long long)(n0 + lrB + srow) * ldb + schk;
    const long long gb1 = gb0 + 16LL * ldb;

    auto stage = [&](int bf, int k0) {
        #pragma unroll
        for (int u = 0; u < KU; ++u) {
            const int ko = k0 + u * 32;
            GL16(Ah + ga0 + ko, &AHs[bf][u][lrA][0]);
            if constexpr (A2) GL16(Ah + ga1 + ko, &AHs[bf][u][lrA + 16][0]);
            if constexpr (TERMS >= 2) {
                GL16(Al + ga0 + ko, &ALs[bf][u][lrA][0]);
                if constexpr (A2) GL16(Al + ga1 + ko, &ALs[bf][u][lrA + 16][0]);
            }
            GL16(Bh + gb0 + ko, &BHs[bf][u][lrB][0]);
            if constexpr (B2) GL16(Bh + gb1 + ko, &BHs[bf][u][lrB + 16][0]);
            if constexpr (TERMS >= 3) {
                GL16(Bl + gb0 + ko, &BLs[bf][u][lrB][0]);
                if constexpr (B2) GL16(Bl + gb1 + ko, &BLs[bf][u][lrB + 16][0]);
            }
        }
    };

    f32x4 acc[MI][4];
    #pragma unroll
    for (int i = 0; i < MI; ++i)
        #pragma unroll
        for (int j = 0; j < 4; ++j) acc[i][j] = f32x4{0.f, 0.f, 0.f, 0.f};

    const int nk = K / (32 * KU);
    int cur = 0;
    stage(0, 0);
    __syncthreads();
    for (int t = 0; t < nk; ++t) {
        if (t + 1 < nk) stage(cur ^ 1, (t + 1) * 32 * KU);
        #pragma unroll
        for (int u = 0; u < KU; ++u) {
            s16x8 ah[MI], al[MI], bh[4], bl[4];
            #pragma unroll
            for (int i = 0; i < MI; ++i)
                ah[i] = *(const s16x8*)&AHs[cur][u][wmB + i * 16 + l16][grp * 8];
            if constexpr (TERMS >= 2) {
                #pragma unroll
                for (int i = 0; i < MI; ++i)
                    al[i] = *(const s16x8*)&ALs[cur][u][wmB + i * 16 + l16][grp * 8];
            }
            #pragma unroll
            for (int j = 0; j < 4; ++j)
                bh[j] = *(const s16x8*)&BHs[cur][u][wnB + j * 16 + l16][grp * 8];
            if constexpr (TERMS >= 3) {
                #pragma unroll
                for (int j = 0; j < 4; ++j)
                    bl[j] = *(const s16x8*)&BLs[cur][u][wnB + j * 16 + l16][grp * 8];
            }
            #pragma unroll
            for (int i = 0; i < MI; ++i) {
                #pragma unroll
                for (int j = 0; j < 4; ++j) {
                    acc[i][j] = mfma16(ah[i], bh[j], acc[i][j]);
                    if constexpr (TERMS >= 3) acc[i][j] = mfma16(ah[i], bl[j], acc[i][j]);
                    if constexpr (TERMS >= 2) acc[i][j] = mfma16(al[i], bh[j], acc[i][j]);
                }
            }
        }
        __syncthreads();
        cur ^= 1;
    }
    // ---- epilogue ----
    #pragma unroll
    for (int i = 0; i < MI; ++i) {
        #pragma unroll
        for (int j = 0; j < 4; ++j) {
            int col = n0 + wnB + j * 16 + l16;
            #pragma unroll
            for (int r = 0; r < 4; ++r) {
                int mr = m0 + wmB + i * 16 + grp * 4 + r;
                if (AMODE != 0 && mr >= cnt) continue;
                long long crow = (AMODE == 0) ? mr : (off + mr);
                float val = acc[i][j][r];
                if (EPI == 0) {
                    ((float*)Cv)[crow * ldc + col] = val;
                } else if (EPI == 1) {
                    ((float*)Cv)[crow * ldc + col] = val + RES[crow * ldc + col];
                } else if (EPI == 2) {
                    ((u16*)Cv)[crow * ldc + col] = f2b(gelu_t(val));
                } else if (EPI == 5) {
                    ((u16*)Cv)[crow * ldc + col] = f2b(val);
                } else {
                    float v2 = val + RES[crow * ldc + col];
                    ((float*)Cv)[crow * ldc + col] = v2;
                    C2[crow * ldc + col] = v2;
                }
            }
        }
    }
}

// -------- K/V prep: K split bf16 (row layout), V^T split bf16 --------
__global__ __launch_bounds__(256) void kvprep(const float* __restrict__ qkvf,
    u16* __restrict__ kTh, u16* __restrict__ kTl,
    u16* __restrict__ vTh, u16* __restrict__ vTl)
{
    __shared__ float tile[64][68];
    const int st = blockIdx.x * 64;
    const int b = blockIdx.y & 1, kvh = blockIdx.y >> 1;
    const int tid = threadIdx.x;
    #pragma unroll
    for (int h = 0; h < 4; ++h) {
        int c = tid + h * 256;
        int srow = c >> 4, dseg = c & 15;
        f32x4 v = *(const f32x4*)(qkvf + (size_t)((st + srow) * BATCH + b) * QKVO
                                  + (NHEAD + NKVH) * HDIM + kvh * HDIM + dseg * 4);
        *(f32x4*)&tile[srow][dseg * 4] = v;
    }
    {
        int row = tid >> 2, qseg = tid & 3;
        const float* kr = qkvf + (size_t)((st + row) * BATCH + b) * QKVO
                          + NHEAD * HDIM + kvh * HDIM + qseg * 16;
        size_t ko = ((size_t)((b * NKVH + kvh) * SEQ + st + row)) * HDIM + qseg * 16;
        #pragma unroll
        for (int c = 0; c < 4; ++c) {
            f32x4 x = *(const f32x4*)(kr + c * 4);
            s16x4 vh, vl;
            #pragma unroll
            for (int j = 0; j < 4; ++j) {
                u16 hb, lb; split2(x[j], hb, lb);
                vh[j] = (short)hb; vl[j] = (short)lb;
            }
            *(s16x4*)(kTh + ko + c * 4) = vh;
            *(s16x4*)(kTl + ko + c * 4) = vl;
        }
    }
    __syncthreads();
    #pragma unroll
    for (int h = 0; h < 2; ++h) {
        int c = tid + h * 256;
        int drow = c >> 3, sseg = c & 7;
        s16x8 vh, vl;
        #pragma unroll
        for (int j = 0; j < 8; ++j) {
            u16 hb, lb; split2(tile[sseg * 8 + j][drow], hb, lb);
            vh[j] = (short)hb; vl[j] = (short)lb;
        }
        size_t oo = ((size_t)((b * NKVH + kvh) * HDIM + drow)) * SEQ + st + sseg * 8;
        *(s16x8*)(vTh + oo) = vh;
        *(s16x8*)(vTl + oo) = vl;
    }
}

// --- Flash attention partials: 1 wave, 32 q-rows, 256-row kv chunk ---
__global__ __launch_bounds__(64, 3) void attn_part(
    const float* __restrict__ qkvf,
    const u16* __restrict__ kTh, const u16* __restrict__ kTl,
    const u16* __restrict__ vTh, const u16* __restrict__ vTl,
    float* __restrict__ part)
{
    __shared__ u16 plh[32][40];
    __shared__ u16 pll[32][40];
    const int p = blockIdx.x;
    int qt, c;
    if (p < 32)      { c = 0; qt = p; }
    else if (p < 56) { c = 1; qt = p - 24; }
    else if (p < 72) { c = 2; qt = p - 40; }
    else             { c = 3; qt = p - 48; }
    const int h = blockIdx.y, b = blockIdx.z;
    const int kvh = h >> 2;
    const int lane = threadIdx.x, l16 = lane & 15, grp = lane >> 4;

    s16x8 qh[2][2], ql[2][2];
    #pragma unroll
    for (int mt = 0; mt < 2; ++mt) {
        const float* qb = qkvf + (size_t)((qt * 32 + mt * 16 + l16) * BATCH + b) * QKVO
                          + h * HDIM + grp * 8;
        #pragma unroll
        for (int ks = 0; ks < 2; ++ks) {
            f32x4 x0 = *(const f32x4*)(qb + ks * 32);
            f32x4 x1 = *(const f32x4*)(qb + ks * 32 + 4);
            #pragma unroll
            for (int j = 0; j < 4; ++j) {
                u16 hb, lb;
                split2(x0[j], hb, lb);
                qh[mt][ks][j] = (short)hb; ql[mt][ks][j] = (short)lb;
                split2(x1[j], hb, lb);
                qh[mt][ks][4 + j] = (short)hb; ql[mt][ks][4 + j] = (short)lb;
            }
        }
    }
    float mrow[2][4], lsum[2][4];
    f32x4 o[2][4];
    #pragma unroll
    for (int mt = 0; mt < 2; ++mt) {
        #pragma unroll
        for (int r = 0; r < 4; ++r) { mrow[mt][r] = -__builtin_inff(); lsum[mt][r] = 0.f; }
        #pragma unroll
        for (int db = 0; db < 4; ++db) o[mt][db] = f32x4{0.f, 0.f, 0.f, 0.f};
    }

    const size_t kvbase = (size_t)(b * NKVH + kvh) * SEQ;
    const int kv0 = c * 256;
    const int kv_hi = min(kv0 + 256, qt * 32 + 32);
    const int nt = (kv_hi - kv0 + 31) >> 5;
    for (int jb = 0; jb < nt; ++jb) {
        const int kvb = kv0 + jb * 32;
        // issue V loads early: independent of P, hide HBM latency under QK+softmax
        s16x8 vhv[4], vlv[4];
        #pragma unroll
        for (int db = 0; db < 4; ++db) {
            size_t vo = ((size_t)((b * NKVH + kvh) * HDIM + db * 16 + l16)) * SEQ + kvb + grp * 8;
            vhv[db] = *(const s16x8*)(vTh + vo);
            vlv[db] = *(const s16x8*)(vTl + vo);
        }
        f32x4 s[2][2];
        #pragma unroll
        for (int t2 = 0; t2 < 2; ++t2) {
            size_t kb = (kvbase + kvb + t2 * 16 + l16) * HDIM + grp * 8;
            f32x4 z0 = f32x4{0.f, 0.f, 0.f, 0.f};
            f32x4 z1 = f32x4{0.f, 0.f, 0.f, 0.f};
            #pragma unroll
            for (int ks = 0; ks < 2; ++ks) {
                s16x8 kh = *(const s16x8*)(kTh + kb + ks * 32);
                s16x8 kl = *(const s16x8*)(kTl + kb + ks * 32);
                z0 = mfma16(qh[0][ks], kh, z0);
                z0 = mfma16(qh[0][ks], kl, z0);
                z0 = mfma16(ql[0][ks], kh, z0);
                z1 = mfma16(qh[1][ks], kh, z1);
                z1 = mfma16(qh[1][ks], kl, z1);
                z1 = mfma16(ql[1][ks], kh, z1);
            }
            s[0][t2] = z0; s[1][t2] = z1;
        }
        #pragma unroll
        for (int mt = 0; mt < 2; ++mt) {
            #pragma unroll
            for (int r = 0; r < 4; ++r) {
                const int qrow = qt * 32 + mt * 16 + grp * 4 + r;
                float a0 = s[mt][0][r] * 0.125f; if (kvb + l16 > qrow) a0 = -__builtin_inff();
                float a1 = s[mt][1][r] * 0.125f; if (kvb + 16 + l16 > qrow) a1 = -__builtin_inff();
                float mx = fmaxf(a0, a1);
                #pragma unroll
                for (int t = 1; t < 16; t <<= 1) mx = fmaxf(mx, __shfl_xor(mx, t));
                float mn = fmaxf(mrow[mt][r], mx);
                float sc = __expf(mrow[mt][r] - mn);
                float p0 = __expf(a0 - mn), p1 = __expf(a1 - mn);
                float ps = p0 + p1;
                #pragma unroll
                for (int t = 1; t < 16; t <<= 1) ps += __shfl_xor(ps, t);
                lsum[mt][r] = lsum[mt][r] * sc + ps;
                mrow[mt][r] = mn;
                s[mt][0][r] = p0; s[mt][1][r] = p1;
                #pragma unroll
                for (int db = 0; db < 4; ++db) o[mt][db][r] *= sc;
            }
        }
        __syncthreads();
        #pragma unroll
        for (int mt = 0; mt < 2; ++mt) {
            #pragma unroll
            for (int t2 = 0; t2 < 2; ++t2) {
                #pragma unroll
                for (int r = 0; r < 4; ++r) {
                    u16 hb, lb; split2(s[mt][t2][r], hb, lb);
                    plh[mt * 16 + grp * 4 + r][t2 * 16 + l16] = hb;
                    pll[mt * 16 + grp * 4 + r][t2 * 16 + l16] = lb;
                }
            }
        }
        __syncthreads();
        s16x8 pah0 = *(const s16x8*)&plh[l16][grp * 8];
        s16x8 pal0 = *(const s16x8*)&pll[l16][grp * 8];
        s16x8 pah1 = *(const s16x8*)&plh[16 + l16][grp * 8];
        s16x8 pal1 = *(const s16x8*)&pll[16 + l16][grp * 8];
        #pragma unroll
        for (int db = 0; db < 4; ++db) {
            o[0][db] = mfma16(pah0, vhv[db], o[0][db]);
            o[0][db] = mfma16(pah0, vlv[db], o[0][db]);
            o[0][db] = mfma16(pal0, vhv[db], o[0][db]);
            o[1][db] = mfma16(pah1, vhv[db], o[1][db]);
            o[1][db] = mfma16(pah1, vlv[db], o[1][db]);
            o[1][db] = mfma16(pal1, vhv[db], o[1][db]);
        }
    }
    float* rec = part + (((size_t)(b * NHEAD + h) * NPART + p) * PREC);
    #pragma unroll
    for (int mt = 0; mt < 2; ++mt) {
        #pragma unroll
        for (int db = 0; db < 4; ++db) {
            #pragma unroll
            for (int r = 0; r < 4; ++r)
                rec[(mt * 16 + grp * 4 + r) * 64 + db * 16 + l16] = o[mt][db][r];
        }
    }
    if (l16 == 0) {
        #pragma unroll
        for (int mt = 0; mt < 2; ++mt) {
            #pragma unroll
            for (int r = 0; r < 4; ++r) {
                rec[2048 + mt * 16 + grp * 4 + r] = mrow[mt][r];
                rec[2080 + mt * 16 + grp * 4 + r] = lsum[mt][r];
            }
        }
    }
}

// ------- combine partials -> split-bf16 attention output -------------
__global__ __launch_bounds__(256) void attn_comb(const float* __restrict__ part,
    u16* __restrict__ attn_h, u16* __restrict__ attn_l)
{
    const int qt16 = blockIdx.x, h = blockIdx.y, b = blockIdx.z;
    const int qt32 = qt16 >> 1;
    const int lrow = (qt16 & 1) * 16 + (threadIdx.x >> 4);
    const int nch = (qt32 >> 3) + 1;
    const int c4 = (threadIdx.x & 15) * 4;
    const size_t base = (size_t)(b * NHEAD + h) * NPART;
    const int pbase[4] = {0, 24, 40, 48};   // p = pbase[c] + qt32
    float mv[4], lv[4];
    float M = -__builtin_inff();
    #pragma unroll
    for (int c = 0; c < 4; ++c) {
        if (c < nch) {
            const float* rec = part + (base + pbase[c] + qt32) * PREC;
            mv[c] = rec[2048 + lrow];
            lv[c] = rec[2080 + lrow];
            M = fmaxf(M, mv[c]);
        }
    }
    float L = 0.f;
    f32x4 acc = f32x4{0.f, 0.f, 0.f, 0.f};
    #pragma unroll
    for (int c = 0; c < 4; ++c) {
        if (c < nch) {
            const float* rec = part + (base + pbase[c] + qt32) * PREC;
            float wgt = __expf(mv[c] - M);
            L += lv[c] * wgt;
            f32x4 ov = *(const f32x4*)(rec + lrow * 64 + c4);
            acc[0] += ov[0] * wgt; acc[1] += ov[1] * wgt;
            acc[2] += ov[2] * wgt; acc[3] += ov[3] * wgt;
        }
    }
    float inv = 1.f / L;
    const int qrow = qt32 * 32 + lrow;
    size_t oo = (size_t)(qrow * BATCH + b) * HID + h * HDIM + c4;
    #pragma unroll
    for (int j = 0; j < 4; ++j) {
        u16 hb, lb; split2(acc[j] * inv, hb, lb);
        attn_h[oo + j] = hb;
        attn_l[oo + j] = lb;
    }
}

// ---------------- Router: logits, softmax, top2 ----------------------
__global__ __launch_bounds__(64) void router_k(const float* __restrict__ ln2,
    const float* __restrict__ rw, int* __restrict__ e01, float* __restrict__ p01)
{
    const int t = blockIdx.x, lane = threadIdx.x;
    const float* xr = ln2 + (size_t)t * HID + lane * 16;
    float x[16];
    #pragma unroll
    for (int c = 0; c < 4; ++c) {
        f32x4 u = *(const f32x4*)(xr + c * 4);
        #pragma unroll
        for (int j = 0; j < 4; ++j) x[c * 4 + j] = u[j];
    }
    float lg[8];
    #pragma unroll
    for (int e = 0; e < 8; ++e) {
        const float* wr = rw + (size_t)e * HID + lane * 16;
        float a = 0.f;
        #pragma unroll
        for (int c = 0; c < 4; ++c) {
            f32x4 wv = *(const f32x4*)(wr + c * 4);
            #pragma unroll
            for (int j = 0; j < 4; ++j) a += x[c * 4 + j] * wv[j];
        }
        #pragma unroll
        for (int off = 32; off >= 1; off >>= 1) a += __shfl_xor(a, off);
        lg[e] = a;
    }
    float mx = lg[0];
    #pragma unroll
    for (int e = 1; e < 8; ++e) mx = fmaxf(mx, lg[e]);
    float pe[8], ssum = 0.f;
    #pragma unroll
    for (int e = 0; e < 8; ++e) { pe[e] = expf(lg[e] - mx); ssum += pe[e]; }
    float inv = 1.f / ssum;
    int e0 = 0; float b0 = -1.f;
    #pragma unroll
    for (int e = 0; e < 8; ++e) { float p = pe[e] * inv; if (p > b0) { b0 = p; e0 = e; } }
    int e1 = -1; float b1 = -1.f;
    #pragma unroll
    for (int e = 0; e < 8; ++e) {
        if (e == e0) continue;
        float p = pe[e] * inv; if (p > b1) { b1 = p; e1 = e; }
    }
    if (lane == 0) {
        e01[2 * t] = e0; e01[2 * t + 1] = e1;
        p01[2 * t] = b0; p01[2 * t + 1] = b1;
    }
}

// --- fused count + prefix + deterministic scatter (8 blocks, 1 wave) -
__global__ __launch_bounds__(64) void scatter_det(const int* __restrict__ e01,
    const float* __restrict__ p01, int* __restrict__ cnt, int* __restrict__ offs,
    int* __restrict__ tok_of, float* __restrict__ slot_p, int* __restrict__ slot_of)
{
    const int e = blockIdx.x;
    const int lane = threadIdx.x;
    // pass 1: count every expert's assignments (unrolled compares, no arrays)
    int myc[8] = {0, 0, 0, 0, 0, 0, 0, 0};
    for (int i = lane; i < 2 * TOK; i += 64) {
        int ei = e01[i];
        #pragma unroll
        for (int ee = 0; ee < 8; ++ee) myc[ee] += (ei == ee) ? 1 : 0;
    }
    #pragma unroll
    for (int ee = 0; ee < 8; ++ee) {
        int v = myc[ee];
        #pragma unroll
        for (int off = 32; off >= 1; off >>= 1) v += __shfl_xor(v, off);
        myc[ee] = v;
    }
    int base = 0;
    #pragma unroll
    for (int ee = 0; ee < 8; ++ee) if (ee < e) base += myc[ee];
    if (lane == 0) { cnt[e] = myc[e]; offs[e] = base; }
    // pass 2: deterministic slot assignment via wave prefix scan
    for (int c = 0; c < TOK; c += 64) {
        int t = c + lane;
        int kk = -1;
        if (e01[2 * t] == e) kk = 0;
        else if (e01[2 * t + 1] == e) kk = 1;
        int f = (kk >= 0) ? 1 : 0;
        int sc = f;
        #pragma unroll
        for (int o = 1; o < 64; o <<= 1) {
            int nn = __shfl_up(sc, o);
            if (lane >= o) sc += nn;
        }
        if (kk >= 0) {
            int slot = base + sc - 1;
            tok_of[slot] = t;
            slot_p[slot] = p01[2 * t + kk];
            slot_of[2 * t + kk] = slot;
        }
        base += __shfl(sc, 63);
    }
}

// ---- final MoE combine: out[t] += p0*y[s0] + p1*y[s1] (y bf16) ------
__global__ __launch_bounds__(256) void moe_comb(const u16* __restrict__ yb,
    const int* __restrict__ slot_of, const float* __restrict__ p01,
    float* __restrict__ out)
{
    const int t = blockIdx.x;
    const int c4 = threadIdx.x * 4;
    const int s0 = slot_of[2 * t], s1 = slot_of[2 * t + 1];
    const float p0 = p01[2 * t], p1 = p01[2 * t + 1];
    s16x4 y0 = *(const s16x4*)(yb + (size_t)s0 * HID + c4);
    s16x4 y1 = *(const s16x4*)(yb + (size_t)s1 * HID + c4);
    f32x4 o = *(f32x4*)(out + (size_t)t * HID + c4);
    #pragma unroll
    for (int j = 0; j < 4; ++j)
        o[j] += p0 * b2f((u16)y0[j]) + p1 * b2f((u16)y1[j]);
    *(f32x4*)(out + (size_t)t * HID + c4) = o;
}

__global__ void sentinel_k(float* out) {
    out[blockIdx.x * 256 + threadIdx.x] = 12345.0f;
}

extern "C" void kernel_launch(void* const* d_in, const int* in_sizes, int n_in,
                              void* d_out, int out_size, void* d_ws, size_t ws_size,
                              hipStream_t stream)
{
    (void)in_sizes; (void)n_in; (void)out_size;
    const float* hs    = (const float*)d_in[0];
    const float* ln1w  = (const float*)d_in[1];
    const float* ln1b  = (const float*)d_in[2];
    const float* ln2w  = (const float*)d_in[3];
    const float* ln2b  = (const float*)d_in[4];
    const float* qkvw  = (const float*)d_in[5];
    const float* projw = (const float*)d_in[6];
    const float* rw    = (const float*)d_in[7];
    const float* w1    = (const float*)d_in[8];
    const float* w2    = (const float*)d_in[9];
    float* out = (float*)d_out;
    char* ws = (char*)d_ws;

    size_t o = 0;
    auto alloc = [&](size_t bytes) -> void* {
        void* p = ws + o; o += (bytes + 255) & ~(size_t)255; return p;
    };
    u16*   w1t    = (u16*)alloc((size_t)NEXP * FFN * HID * 2);   // [E][F][H]; early: partials
    u16*   w2t    = (u16*)alloc((size_t)NEXP * HID * FFN * 2);   // [E][H][F]
    u16*   qkvwh  = (u16*)alloc((size_t)QKVO * HID * 2);
    u16*   qkvwl  = (u16*)alloc((size_t)QKVO * HID * 2);
    u16*   projwh = (u16*)alloc((size_t)HID * HID * 2);
    u16*   projwl = (u16*)alloc((size_t)HID * HID * 2);
    u16*   ln1h   = (u16*)alloc((size_t)TOK * HID * 2);          // also attnh
    u16*   ln1l   = (u16*)alloc((size_t)TOK * HID * 2);          // also attnl
    float* qkvf   = (float*)alloc((size_t)TOK * QKVO * 4);       // also ln2f, then yb
    u16*   kTh    = (u16*)alloc((size_t)BATCH * NKVH * SEQ * HDIM * 2);
    u16*   kTl    = (u16*)alloc((size_t)BATCH * NKVH * SEQ * HDIM * 2);
    u16*   vTh    = (u16*)alloc((size_t)BATCH * NKVH * HDIM * SEQ * 2);
    u16*   vTl    = (u16*)alloc((size_t)BATCH * NKVH * HDIM * SEQ * 2);
    float* haf    = (float*)alloc((size_t)TOK * HID * 4);
    u16*   ln2h   = (u16*)alloc((size_t)TOK * HID * 2);
    u16*   a1b    = (u16*)alloc((size_t)TOK * 2 * FFN * 2);
    int*   e01    = (int*)alloc(TOK * 2 * 4);
    float* p01    = (float*)alloc(TOK * 2 * 4);
    int*   cnt    = (int*)alloc(256);
    int*   offs   = (int*)alloc(256);
    int*   tok_of = (int*)alloc(TOK * 2 * 4);
    float* slot_p = (float*)alloc(TOK * 2 * 4);
    int*   slot_of = (int*)alloc(TOK * 2 * 4);
    size_t need = o;

    if (ws_size < need) {
        sentinel_k<<<TOK * HID / 256, 256, 0, stream>>>(out);
        return;
    }

    u16* attnh = ln1h;
    u16* attnl = ln1l;
    float* ln2f = qkvf;
    u16*  yb = (u16*)qkvf;       // 8.4MB, region dead after router_k
    float* part = (float*)w1t;   // 21.6 MB partials; w1t written only later

    // weight prep needed before attention
    split_cast_k<<<QKVO * HID / 4 / 256, 256, 0, stream>>>(qkvw, qkvwh, qkvwl);
    split_cast_k<<<HID * HID / 4 / 256, 256, 0, stream>>>(projw, projwh, projwl);
    // LN1 -> split hi/lo
    ln_k<2><<<TOK, 256, 0, stream>>>(hs, ln1w, ln1b, nullptr, ln1h, ln1l);
    // QKV (3-term, 64x64 tile -> 768 blocks, KU=1)
    gemm_db<0, 3, 0, 2, 1><<<dim3(QKVO / 64, TOK / 64, 1), 256, 0, stream>>>(
        ln1h, ln1l, qkvwh, qkvwl, qkvf, nullptr, nullptr, nullptr, nullptr, nullptr, nullptr,
        TOK, QKVO, HID, HID, HID, QKVO, 0);
    kvprep<<<dim3(SEQ / 64, BATCH * NKVH), 256, 0, stream>>>(qkvf, kTh, kTl, vTh, vTl);
    // split-KV flash attention: 32 q-rows per wave, 256-row kv chunks
    attn_part<<<dim3(NPART, NHEAD, BATCH), 64, 0, stream>>>(
        qkvf, kTh, kTl, vTh, vTl, part);
    attn_comb<<<dim3(SEQ / 16, NHEAD, BATCH), 256, 0, stream>>>(part, attnh, attnl);
    // proj + residual -> haf AND out (3-term, 64x64 tile, KU=1)
    gemm_db<0, 3, 4, 2, 1><<<dim3(HID / 64, TOK / 64, 1), 256, 0, stream>>>(
        attnh, attnl, projwh, projwl, haf, hs, out, nullptr, nullptr, nullptr, nullptr,
        TOK, HID, HID, HID, HID, HID, 0);
    // LN2 -> f32 (router) + hi only (FC1 is 1-term)
    ln_k<4><<<TOK, 256, 0, stream>>>(haf, ln2w, ln2b, ln2f, ln2h, nullptr);
    // MoE weight prep (after partials are dead)
    trans_cast_k<<<dim3(FFN / 64, HID / 64, NEXP), 256, 0, stream>>>(w1, w1t, HID, FFN);
    trans_cast_k<<<dim3(HID / 64, FFN / 64, NEXP), 256, 0, stream>>>(w2, w2t, FFN, HID);
    // router + fused deterministic bucketing (counts + prefix + scatter)
    router_k<<<TOK, 64, 0, stream>>>(ln2f, rw, e01, p01);
    scatter_det<<<NEXP, 64, 0, stream>>>(e01, p01, cnt, offs, tok_of, slot_p, slot_of);
    // FC1 (1-term, gather rows, gelu->bf16, 128x64 tile, KU=2 -> 48KB LDS)
    gemm_db<1, 1, 2, 1, 2><<<dim3(FFN / 64, TOK / 128, NEXP), 256, 0, stream>>>(
        ln2h, nullptr, w1t, nullptr, a1b, nullptr, nullptr, tok_of, offs, cnt, nullptr,
        0, FFN, HID, HID, HID, FFN, (long long)FFN * HID);
    // FC2 (1-term, contig rows, bf16 y store, 128x64 tile, KU=2 -> 48KB LDS)
    gemm_db<2, 1, 5, 1, 2><<<dim3(HID / 64, TOK / 128, NEXP), 256, 0, stream>>>(
        a1b, nullptr, w2t, nullptr, yb, nullptr, nullptr, tok_of, offs, cnt, slot_p,
        0, HID, FFN, FFN, FFN, HID, (long long)HID * FFN);
    // final combine: out += p0*y0 + p1*y1
    moe_comb<<<TOK, 256, 0, stream>>>(yb, slot_of, p01, out);
}

// Round 16
// 316.957 us; speedup vs baseline: 1.1186x; 1.0291x over previous
//
#include <hip/hip_runtime.h>
#include <hip/hip_bf16.h>

typedef unsigned short u16;
typedef __attribute__((ext_vector_type(8))) short s16x8;
typedef __attribute__((ext_vector_type(4))) short s16x4;
typedef __attribute__((ext_vector_type(4))) float f32x4;

#define SEQ 1024
#define BATCH 2
#define HID 1024
#define NHEAD 16
#define NKVH 4
#define HDIM 64
#define NEXP 8
#define FFN 2048
#define TOK (SEQ*BATCH)
#define QKVO ((NHEAD + 2*NKVH)*HDIM)   // 1536
#define NPART 80                        // 32-row q-tiles, 256-row kv chunks
#define PREC 2112                       // 32*64 o + 32 m + 32 l

// async global->LDS, 16B per lane, dest = uniform base + lane*16
#define GL16(gp, lp) __builtin_amdgcn_global_load_lds( \
    (const __attribute__((address_space(1))) unsigned int*)(gp), \
    (__attribute__((address_space(3))) unsigned int*)(lp), 16, 0, 0)

__device__ __forceinline__ float b2f(u16 u) {
    unsigned int x = ((unsigned int)u) << 16;
    return __uint_as_float(x);
}
__device__ __forceinline__ u16 f2b(float f) {
    unsigned int x = __float_as_uint(f);
    x = (x + 0x7FFFu + ((x >> 16) & 1u)) >> 16;
    return (u16)x;
}
__device__ __forceinline__ void split2(float x, u16& hi, u16& lo) {
    hi = f2b(x);
    lo = f2b(x - b2f(hi));
}
__device__ __forceinline__ f32x4 mfma16(s16x8 a, s16x8 b, f32x4 c) {
    return __builtin_amdgcn_mfma_f32_16x16x32_bf16(a, b, c, 0, 0, 0);
}
__device__ __forceinline__ float gelu_t(float x) {
    float x3 = x * x * x;
    return 0.5f * x * (1.0f + tanhf(0.7978845608028654f * (x + 0.044715f * x3)));
}

// ------- LayerNorm: f32 in; OUTMODE: 0=f32, 2=hi/lo, 3=f32+hi/lo, 4=f32+hi -
template<int OUTMODE>
__global__ __launch_bounds__(256) void ln_k(const float* __restrict__ xin,
    const float* __restrict__ wgt, const float* __restrict__ bia,
    float* __restrict__ outf, u16* __restrict__ outh, u16* __restrict__ outl)
{
    __shared__ float red[8];
    const int t = blockIdx.x, tid = threadIdx.x;
    f32x4 u = *((const f32x4*)(xin + (size_t)t * HID) + tid);
    float s = u[0] + u[1] + u[2] + u[3];
    #pragma unroll
    for (int off = 32; off >= 1; off >>= 1) s += __shfl_xor(s, off);
    if ((tid & 63) == 0) red[tid >> 6] = s;
    __syncthreads();
    float mu = (red[0] + red[1] + red[2] + red[3]) * (1.0f / HID);
    float d0 = u[0]-mu, d1 = u[1]-mu, d2 = u[2]-mu, d3 = u[3]-mu;
    float ss = d0*d0 + d1*d1 + d2*d2 + d3*d3;
    #pragma unroll
    for (int off = 32; off >= 1; off >>= 1) ss += __shfl_xor(ss, off);
    if ((tid & 63) == 0) red[4 + (tid >> 6)] = ss;
    __syncthreads();
    float var = (red[4] + red[5] + red[6] + red[7]) * (1.0f / HID);
    float rs = 1.0f / sqrtf(var + 1e-5f);
    f32x4 wv = *((const f32x4*)wgt + tid);
    f32x4 bv = *((const f32x4*)bia + tid);
    f32x4 o;
    o[0] = d0*rs*wv[0] + bv[0];
    o[1] = d1*rs*wv[1] + bv[1];
    o[2] = d2*rs*wv[2] + bv[2];
    o[3] = d3*rs*wv[3] + bv[3];
    if (OUTMODE == 0 || OUTMODE >= 3)
        *((f32x4*)(outf + (size_t)t * HID) + tid) = o;
    if (OUTMODE == 2 || OUTMODE == 3) {
        s16x4 h, l;
        #pragma unroll
        for (int j = 0; j < 4; ++j) {
            u16 hb, lb; split2(o[j], hb, lb);
            h[j] = (short)hb; l[j] = (short)lb;
        }
        *((s16x4*)(outh + (size_t)t * HID) + tid) = h;
        *((s16x4*)(outl + (size_t)t * HID) + tid) = l;
    }
    if (OUTMODE == 4) {
        s16x4 h;
        #pragma unroll
        for (int j = 0; j < 4; ++j) h[j] = (short)f2b(o[j]);
        *((s16x4*)(outh + (size_t)t * HID) + tid) = h;
    }
}

// -------- weight prep: split-cast f32 -> bf16 hi/lo (same layout) ----
__global__ __launch_bounds__(256) void split_cast_k(const float* __restrict__ in,
    u16* __restrict__ hi, u16* __restrict__ lo)
{
    int i = blockIdx.x * 256 + threadIdx.x;
    f32x4 v = ((const f32x4*)in)[i];
    s16x4 h, l;
    #pragma unroll
    for (int j = 0; j < 4; ++j) {
        u16 hb, lb; split2(v[j], hb, lb);
        h[j] = (short)hb; l[j] = (short)lb;
    }
    ((s16x4*)hi)[i] = h;
    ((s16x4*)lo)[i] = l;
}

// -------- weight prep: transpose-cast f32 [E][R][C] -> bf16 [E][C][R]
__global__ __launch_bounds__(256) void trans_cast_k(const float* __restrict__ in,
    u16* __restrict__ out, int R, int C)
{
    __shared__ float tile[64][65];
    const int e = blockIdx.z;
    const float* src = in + (size_t)e * R * C;
    u16* dst = out + (size_t)e * C * R;
    const int r0 = blockIdx.y * 64, c0 = blockIdx.x * 64;
    const int tr = threadIdx.x >> 2, tc = (threadIdx.x & 3) * 16;
    #pragma unroll
    for (int j = 0; j < 4; ++j) {
        f32x4 v = *(const f32x4*)(src + (size_t)(r0 + tr) * C + c0 + tc + j * 4);
        *(f32x4*)&tile[tr][tc + j * 4] = v;
    }
    __syncthreads();
    s16x8 o0, o1;
    #pragma unroll
    for (int j = 0; j < 8; ++j) o0[j] = (short)f2b(tile[tc + j][tr]);
    #pragma unroll
    for (int j = 0; j < 8; ++j) o1[j] = (short)f2b(tile[tc + 8 + j][tr]);
    u16* dp = dst + (size_t)(c0 + tr) * R + r0 + tc;
    *(s16x8*)dp = o0;
    *(s16x8*)(dp + 8) = o1;
}

// ------ gemm_db: bf16 MFMA GEMM, global_load_lds + double buffer -----
// TERMS: 1 = AhBh ; 2 = + AlBh ; 3 = + AhBl
// AMODE: 0 plain rows; 1 gather rows glist[off+r]; 2 contiguous off+r
// EPI: 0 f32; 1 f32+RES; 2 bf16(gelu); 4 f32+RES dual; 5 bf16 plain
// TILE: 0 = 128x128; 1 = 128x64; 2 = 64x64
// KU: K-chunks (x32) staged per barrier iteration
template<int AMODE, int TERMS, int EPI, int TILE, int KU>
__global__ __launch_bounds__(256, 2) void gemm_db(
    const u16* __restrict__ Ah, const u16* __restrict__ Al,
    const u16* __restrict__ Bh, const u16* __restrict__ Bl,
    void* __restrict__ Cv, const float* __restrict__ RES, float* __restrict__ C2,
    const int* __restrict__ glist, const int* __restrict__ offs,
    const int* __restrict__ cnts, const float* __restrict__ slot_p,
    int M, int N, int K, int lda, int ldb, int ldc, long long bStrideE)
{
    constexpr int BM = (TILE == 2) ? 64 : 128;
    constexpr int BN = (TILE == 0) ? 128 : 64;
    constexpr int MI = (TILE == 0) ? 4 : ((TILE == 1) ? 2 : 1);
    constexpr bool A2 = (BM == 128);
    constexpr bool B2 = (BN == 128);
    __shared__ u16 AHs[2][KU][BM][32];
    __shared__ u16 ALs[(TERMS >= 2) ? 2 : 1][(TERMS >= 2) ? KU : 1][(TERMS >= 2) ? BM : 1][32];
    __shared__ u16 BHs[2][KU][BN][32];
    __shared__ u16 BLs[(TERMS >= 3) ? 2 : 1][(TERMS >= 3) ? KU : 1][(TERMS >= 3) ? BN : 1][32];

    const int tid = threadIdx.x;
    const int m0 = blockIdx.y * BM;
    const int n0 = blockIdx.x * BN;
    int off = 0, cnt = M;
    if (AMODE != 0) {
        const int e = blockIdx.z;
        off = offs[e]; cnt = cnts[e];
        if (m0 >= cnt) return;
        long long be = (long long)e * bStrideE;
        Bh += be;
        if (TERMS >= 3) Bl += be;
    }
    const int lane = tid & 63, w = tid >> 6;
    const int wmB = (TILE == 0) ? ((w >> 1) * 64) : (w * (BM / 4));
    const int wnB = (TILE == 0) ? ((w & 1) * 64) : 0;
    const int l16 = lane & 15, grp = lane >> 4;
    const int srow = lane >> 2, schk = (lane & 3) * 8;
    const int lrA = w * (BM / 4);
    const int lrB = w * (BN / 4);

    long long ga0, ga1 = 0;
    {
        int am0 = m0 + lrA + srow;
        int am1 = am0 + 16;
        long long r0, r1;
        if (AMODE == 0) { r0 = am0; r1 = am1; }
        else if (AMODE == 1) {
            r0 = glist[off + ((am0 < cnt) ? am0 : 0)];
            r1 = A2 ? glist[off + ((am1 < cnt) ? am1 : 0)] : 0;
        } else {
            r0 = off + ((am0 < cnt) ? am0 : 0);
            r1 = A2 ? (off + ((am1 < cnt) ? am1 : 0)) : 0;
        }
        ga0 = r0 * lda + schk;
        if (A2) ga1 = r1 * lda + schk;
    }
    const long long gb0 = (long long)(n0 + lrB + srow) * ldb + schk;
    const long long gb1 = gb0 + 16LL * ldb;

    auto stage = [&](int bf, int k0) {
        #pragma unroll
        for (int u = 0; u < KU; ++u) {
            const int ko = k0 + u * 32;
            GL16(Ah + ga0 + ko, &AHs[bf][u][lrA][0]);
            if constexpr (A2) GL16(Ah + ga1 + ko, &AHs[bf][u][lrA + 16][0]);
            if constexpr (TERMS >= 2) {
                GL16(Al + ga0 + ko, &ALs[bf][u][lrA][0]);
                if constexpr (A2) GL16(Al + ga1 + ko, &ALs[bf][u][lrA + 16][0]);
            }
            GL16(Bh + gb0 + ko, &BHs[bf][u][lrB][0]);
            if constexpr (B2) GL16(Bh + gb1 + ko, &BHs[bf][u][lrB + 16][0]);
            if constexpr (TERMS >= 3) {
                GL16(Bl + gb0 + ko, &BLs[bf][u][lrB][0]);
                if constexpr (B2) GL16(Bl + gb1 + ko, &BLs[bf][u][lrB + 16][0]);
            }
        }
    };

    f32x4 acc[MI][4];
    #pragma unroll
    for (int i = 0; i < MI; ++i)
        #pragma unroll
        for (int j = 0; j < 4; ++j) acc[i][j] = f32x4{0.f, 0.f, 0.f, 0.f};

    const int nk = K / (32 * KU);
    int cur = 0;
    stage(0, 0);
    __syncthreads();
    for (int t = 0; t < nk; ++t) {
        if (t + 1 < nk) stage(cur ^ 1, (t + 1) * 32 * KU);
        #pragma unroll
        for (int u = 0; u < KU; ++u) {
            s16x8 ah[MI], al[MI], bh[4], bl[4];
            #pragma unroll
            for (int i = 0; i < MI; ++i)
                ah[i] = *(const s16x8*)&AHs[cur][u][wmB + i * 16 + l16][grp * 8];
            if constexpr (TERMS >= 2) {
                #pragma unroll
                for (int i = 0; i < MI; ++i)
                    al[i] = *(const s16x8*)&ALs[cur][u][wmB + i * 16 + l16][grp * 8];
            }
            #pragma unroll
            for (int j = 0; j < 4; ++j)
                bh[j] = *(const s16x8*)&BHs[cur][u][wnB + j * 16 + l16][grp * 8];
            if constexpr (TERMS >= 3) {
                #pragma unroll
                for (int j = 0; j < 4; ++j)
                    bl[j] = *(const s16x8*)&BLs[cur][u][wnB + j * 16 + l16][grp * 8];
            }
            #pragma unroll
            for (int i = 0; i < MI; ++i) {
                #pragma unroll
                for (int j = 0; j < 4; ++j) {
                    acc[i][j] = mfma16(ah[i], bh[j], acc[i][j]);
                    if constexpr (TERMS >= 3) acc[i][j] = mfma16(ah[i], bl[j], acc[i][j]);
                    if constexpr (TERMS >= 2) acc[i][j] = mfma16(al[i], bh[j], acc[i][j]);
                }
            }
        }
        __syncthreads();
        cur ^= 1;
    }
    // ---- epilogue ----
    #pragma unroll
    for (int i = 0; i < MI; ++i) {
        #pragma unroll
        for (int j = 0; j < 4; ++j) {
            int col = n0 + wnB + j * 16 + l16;
            #pragma unroll
            for (int r = 0; r < 4; ++r) {
                int mr = m0 + wmB + i * 16 + grp * 4 + r;
                if (AMODE != 0 && mr >= cnt) continue;
                long long crow = (AMODE == 0) ? mr : (off + mr);
                float val = acc[i][j][r];
                if (EPI == 0) {
                    ((float*)Cv)[crow * ldc + col] = val;
                } else if (EPI == 1) {
                    ((float*)Cv)[crow * ldc + col] = val + RES[crow * ldc + col];
                } else if (EPI == 2) {
                    ((u16*)Cv)[crow * ldc + col] = f2b(gelu_t(val));
                } else if (EPI == 5) {
                    ((u16*)Cv)[crow * ldc + col] = f2b(val);
                } else {
                    float v2 = val + RES[crow * ldc + col];
                    ((float*)Cv)[crow * ldc + col] = v2;
                    C2[crow * ldc + col] = v2;
                }
            }
        }
    }
}

// -------- K/V prep: K split bf16 (row layout), V^T split bf16 --------
__global__ __launch_bounds__(256) void kvprep(const float* __restrict__ qkvf,
    u16* __restrict__ kTh, u16* __restrict__ kTl,
    u16* __restrict__ vTh, u16* __restrict__ vTl)
{
    __shared__ float tile[64][68];
    const int st = blockIdx.x * 64;
    const int b = blockIdx.y & 1, kvh = blockIdx.y >> 1;
    const int tid = threadIdx.x;
    #pragma unroll
    for (int h = 0; h < 4; ++h) {
        int c = tid + h * 256;
        int srow = c >> 4, dseg = c & 15;
        f32x4 v = *(const f32x4*)(qkvf + (size_t)((st + srow) * BATCH + b) * QKVO
                                  + (NHEAD + NKVH) * HDIM + kvh * HDIM + dseg * 4);
        *(f32x4*)&tile[srow][dseg * 4] = v;
    }
    {
        int row = tid >> 2, qseg = tid & 3;
        const float* kr = qkvf + (size_t)((st + row) * BATCH + b) * QKVO
                          + NHEAD * HDIM + kvh * HDIM + qseg * 16;
        size_t ko = ((size_t)((b * NKVH + kvh) * SEQ + st + row)) * HDIM + qseg * 16;
        #pragma unroll
        for (int c = 0; c < 4; ++c) {
            f32x4 x = *(const f32x4*)(kr + c * 4);
            s16x4 vh, vl;
            #pragma unroll
            for (int j = 0; j < 4; ++j) {
                u16 hb, lb; split2(x[j], hb, lb);
                vh[j] = (short)hb; vl[j] = (short)lb;
            }
            *(s16x4*)(kTh + ko + c * 4) = vh;
            *(s16x4*)(kTl + ko + c * 4) = vl;
        }
    }
    __syncthreads();
    #pragma unroll
    for (int h = 0; h < 2; ++h) {
        int c = tid + h * 256;
        int drow = c >> 3, sseg = c & 7;
        s16x8 vh, vl;
        #pragma unroll
        for (int j = 0; j < 8; ++j) {
            u16 hb, lb; split2(tile[sseg * 8 + j][drow], hb, lb);
            vh[j] = (short)hb; vl[j] = (short)lb;
        }
        size_t oo = ((size_t)((b * NKVH + kvh) * HDIM + drow)) * SEQ + st + sseg * 8;
        *(s16x8*)(vTh + oo) = vh;
        *(s16x8*)(vTl + oo) = vl;
    }
}

// --- Flash attention partials: 1 wave, 32 q-rows, 256-row kv chunk ---
__global__ __launch_bounds__(64, 3) void attn_part(
    const float* __restrict__ qkvf,
    const u16* __restrict__ kTh, const u16* __restrict__ kTl,
    const u16* __restrict__ vTh, const u16* __restrict__ vTl,
    float* __restrict__ part)
{
    __shared__ u16 plh[32][40];
    __shared__ u16 pll[32][40];
    const int p = blockIdx.x;
    int qt, c;
    if (p < 32)      { c = 0; qt = p; }
    else if (p < 56) { c = 1; qt = p - 24; }
    else if (p < 72) { c = 2; qt = p - 40; }
    else             { c = 3; qt = p - 48; }
    const int h = blockIdx.y, b = blockIdx.z;
    const int kvh = h >> 2;
    const int lane = threadIdx.x, l16 = lane & 15, grp = lane >> 4;

    s16x8 qh[2][2], ql[2][2];
    #pragma unroll
    for (int mt = 0; mt < 2; ++mt) {
        const float* qb = qkvf + (size_t)((qt * 32 + mt * 16 + l16) * BATCH + b) * QKVO
                          + h * HDIM + grp * 8;
        #pragma unroll
        for (int ks = 0; ks < 2; ++ks) {
            f32x4 x0 = *(const f32x4*)(qb + ks * 32);
            f32x4 x1 = *(const f32x4*)(qb + ks * 32 + 4);
            #pragma unroll
            for (int j = 0; j < 4; ++j) {
                u16 hb, lb;
                split2(x0[j], hb, lb);
                qh[mt][ks][j] = (short)hb; ql[mt][ks][j] = (short)lb;
                split2(x1[j], hb, lb);
                qh[mt][ks][4 + j] = (short)hb; ql[mt][ks][4 + j] = (short)lb;
            }
        }
    }
    float mrow[2][4], lsum[2][4];
    f32x4 o[2][4];
    #pragma unroll
    for (int mt = 0; mt < 2; ++mt) {
        #pragma unroll
        for (int r = 0; r < 4; ++r) { mrow[mt][r] = -__builtin_inff(); lsum[mt][r] = 0.f; }
        #pragma unroll
        for (int db = 0; db < 4; ++db) o[mt][db] = f32x4{0.f, 0.f, 0.f, 0.f};
    }

    const size_t kvbase = (size_t)(b * NKVH + kvh) * SEQ;
    const int kv0 = c * 256;
    const int kv_hi = min(kv0 + 256, qt * 32 + 32);
    const int nt = (kv_hi - kv0 + 31) >> 5;
    for (int jb = 0; jb < nt; ++jb) {
        const int kvb = kv0 + jb * 32;
        f32x4 s[2][2];
        #pragma unroll
        for (int t2 = 0; t2 < 2; ++t2) {
            size_t kb = (kvbase + kvb + t2 * 16 + l16) * HDIM + grp * 8;
            f32x4 z0 = f32x4{0.f, 0.f, 0.f, 0.f};
            f32x4 z1 = f32x4{0.f, 0.f, 0.f, 0.f};
            #pragma unroll
            for (int ks = 0; ks < 2; ++ks) {
                s16x8 kh = *(const s16x8*)(kTh + kb + ks * 32);
                s16x8 kl = *(const s16x8*)(kTl + kb + ks * 32);
                z0 = mfma16(qh[0][ks], kh, z0);
                z0 = mfma16(qh[0][ks], kl, z0);
                z0 = mfma16(ql[0][ks], kh, z0);
                z1 = mfma16(qh[1][ks], kh, z1);
                z1 = mfma16(qh[1][ks], kl, z1);
                z1 = mfma16(ql[1][ks], kh, z1);
            }
            s[0][t2] = z0; s[1][t2] = z1;
        }
        #pragma unroll
        for (int mt = 0; mt < 2; ++mt) {
            #pragma unroll
            for (int r = 0; r < 4; ++r) {
                const int qrow = qt * 32 + mt * 16 + grp * 4 + r;
                float a0 = s[mt][0][r] * 0.125f; if (kvb + l16 > qrow) a0 = -__builtin_inff();
                float a1 = s[mt][1][r] * 0.125f; if (kvb + 16 + l16 > qrow) a1 = -__builtin_inff();
                float mx = fmaxf(a0, a1);
                #pragma unroll
                for (int t = 1; t < 16; t <<= 1) mx = fmaxf(mx, __shfl_xor(mx, t));
                float mn = fmaxf(mrow[mt][r], mx);
                float sc = __expf(mrow[mt][r] - mn);
                float p0 = __expf(a0 - mn), p1 = __expf(a1 - mn);
                float ps = p0 + p1;
                #pragma unroll
                for (int t = 1; t < 16; t <<= 1) ps += __shfl_xor(ps, t);
                lsum[mt][r] = lsum[mt][r] * sc + ps;
                mrow[mt][r] = mn;
                s[mt][0][r] = p0; s[mt][1][r] = p1;
                #pragma unroll
                for (int db = 0; db < 4; ++db) o[mt][db][r] *= sc;
            }
        }
        __syncthreads();
        #pragma unroll
        for (int mt = 0; mt < 2; ++mt) {
            #pragma unroll
            for (int t2 = 0; t2 < 2; ++t2) {
                #pragma unroll
                for (int r = 0; r < 4; ++r) {
                    u16 hb, lb; split2(s[mt][t2][r], hb, lb);
                    plh[mt * 16 + grp * 4 + r][t2 * 16 + l16] = hb;
                    pll[mt * 16 + grp * 4 + r][t2 * 16 + l16] = lb;
                }
            }
        }
        __syncthreads();
        s16x8 pah0 = *(const s16x8*)&plh[l16][grp * 8];
        s16x8 pal0 = *(const s16x8*)&pll[l16][grp * 8];
        s16x8 pah1 = *(const s16x8*)&plh[16 + l16][grp * 8];
        s16x8 pal1 = *(const s16x8*)&pll[16 + l16][grp * 8];
        #pragma unroll
        for (int db = 0; db < 4; ++db) {
            size_t vo = ((size_t)((b * NKVH + kvh) * HDIM + db * 16 + l16)) * SEQ + kvb + grp * 8;
            s16x8 vh = *(const s16x8*)(vTh + vo);
            s16x8 vl = *(const s16x8*)(vTl + vo);
            o[0][db] = mfma16(pah0, vh, o[0][db]);
            o[0][db] = mfma16(pah0, vl, o[0][db]);
            o[0][db] = mfma16(pal0, vh, o[0][db]);
            o[1][db] = mfma16(pah1, vh, o[1][db]);
            o[1][db] = mfma16(pah1, vl, o[1][db]);
            o[1][db] = mfma16(pal1, vh, o[1][db]);
        }
    }
    float* rec = part + (((size_t)(b * NHEAD + h) * NPART + p) * PREC);
    #pragma unroll
    for (int mt = 0; mt < 2; ++mt) {
        #pragma unroll
        for (int db = 0; db < 4; ++db) {
            #pragma unroll
            for (int r = 0; r < 4; ++r)
                rec[(mt * 16 + grp * 4 + r) * 64 + db * 16 + l16] = o[mt][db][r];
        }
    }
    if (l16 == 0) {
        #pragma unroll
        for (int mt = 0; mt < 2; ++mt) {
            #pragma unroll
            for (int r = 0; r < 4; ++r) {
                rec[2048 + mt * 16 + grp * 4 + r] = mrow[mt][r];
                rec[2080 + mt * 16 + grp * 4 + r] = lsum[mt][r];
            }
        }
    }
}

// ------- combine partials -> split-bf16 attention output -------------
__global__ __launch_bounds__(256) void attn_comb(const float* __restrict__ part,
    u16* __restrict__ attn_h, u16* __restrict__ attn_l)
{
    const int qt16 = blockIdx.x, h = blockIdx.y, b = blockIdx.z;
    const int qt32 = qt16 >> 1;
    const int lrow = (qt16 & 1) * 16 + (threadIdx.x >> 4);
    const int nch = (qt32 >> 3) + 1;
    const int c4 = (threadIdx.x & 15) * 4;
    const size_t base = (size_t)(b * NHEAD + h) * NPART;
    const int pbase[4] = {0, 24, 40, 48};   // p = pbase[c] + qt32
    float mv[4], lv[4];
    float M = -__builtin_inff();
    #pragma unroll
    for (int c = 0; c < 4; ++c) {
        if (c < nch) {
            const float* rec = part + (base + pbase[c] + qt32) * PREC;
            mv[c] = rec[2048 + lrow];
            lv[c] = rec[2080 + lrow];
            M = fmaxf(M, mv[c]);
        }
    }
    float L = 0.f;
    f32x4 acc = f32x4{0.f, 0.f, 0.f, 0.f};
    #pragma unroll
    for (int c = 0; c < 4; ++c) {
        if (c < nch) {
            const float* rec = part + (base + pbase[c] + qt32) * PREC;
            float wgt = __expf(mv[c] - M);
            L += lv[c] * wgt;
            f32x4 ov = *(const f32x4*)(rec + lrow * 64 + c4);
            acc[0] += ov[0] * wgt; acc[1] += ov[1] * wgt;
            acc[2] += ov[2] * wgt; acc[3] += ov[3] * wgt;
        }
    }
    float inv = 1.f / L;
    const int qrow = qt32 * 32 + lrow;
    size_t oo = (size_t)(qrow * BATCH + b) * HID + h * HDIM + c4;
    #pragma unroll
    for (int j = 0; j < 4; ++j) {
        u16 hb, lb; split2(acc[j] * inv, hb, lb);
        attn_h[oo + j] = hb;
        attn_l[oo + j] = lb;
    }
}

// ---------------- Router: logits, softmax, top2 ----------------------
__global__ __launch_bounds__(64) void router_k(const float* __restrict__ ln2,
    const float* __restrict__ rw, int* __restrict__ e01, float* __restrict__ p01)
{
    const int t = blockIdx.x, lane = threadIdx.x;
    const float* xr = ln2 + (size_t)t * HID + lane * 16;
    float x[16];
    #pragma unroll
    for (int c = 0; c < 4; ++c) {
        f32x4 u = *(const f32x4*)(xr + c * 4);
        #pragma unroll
        for (int j = 0; j < 4; ++j) x[c * 4 + j] = u[j];
    }
    float lg[8];
    #pragma unroll
    for (int e = 0; e < 8; ++e) {
        const float* wr = rw + (size_t)e * HID + lane * 16;
        float a = 0.f;
        #pragma unroll
        for (int c = 0; c < 4; ++c) {
            f32x4 wv = *(const f32x4*)(wr + c * 4);
            #pragma unroll
            for (int j = 0; j < 4; ++j) a += x[c * 4 + j] * wv[j];
        }
        #pragma unroll
        for (int off = 32; off >= 1; off >>= 1) a += __shfl_xor(a, off);
        lg[e] = a;
    }
    float mx = lg[0];
    #pragma unroll
    for (int e = 1; e < 8; ++e) mx = fmaxf(mx, lg[e]);
    float pe[8], ssum = 0.f;
    #pragma unroll
    for (int e = 0; e < 8; ++e) { pe[e] = expf(lg[e] - mx); ssum += pe[e]; }
    float inv = 1.f / ssum;
    int e0 = 0; float b0 = -1.f;
    #pragma unroll
    for (int e = 0; e < 8; ++e) { float p = pe[e] * inv; if (p > b0) { b0 = p; e0 = e; } }
    int e1 = -1; float b1 = -1.f;
    #pragma unroll
    for (int e = 0; e < 8; ++e) {
        if (e == e0) continue;
        float p = pe[e] * inv; if (p > b1) { b1 = p; e1 = e; }
    }
    if (lane == 0) {
        e01[2 * t] = e0; e01[2 * t + 1] = e1;
        p01[2 * t] = b0; p01[2 * t + 1] = b1;
    }
}

// --- fused count + prefix + deterministic scatter (8 blocks, 1 wave) -
__global__ __launch_bounds__(64) void scatter_det(const int* __restrict__ e01,
    const float* __restrict__ p01, int* __restrict__ cnt, int* __restrict__ offs,
    int* __restrict__ tok_of, float* __restrict__ slot_p, int* __restrict__ slot_of)
{
    const int e = blockIdx.x;
    const int lane = threadIdx.x;
    // pass 1: count every expert's assignments (unrolled compares, no arrays)
    int myc[8] = {0, 0, 0, 0, 0, 0, 0, 0};
    for (int i = lane; i < 2 * TOK; i += 64) {
        int ei = e01[i];
        #pragma unroll
        for (int ee = 0; ee < 8; ++ee) myc[ee] += (ei == ee) ? 1 : 0;
    }
    #pragma unroll
    for (int ee = 0; ee < 8; ++ee) {
        int v = myc[ee];
        #pragma unroll
        for (int off = 32; off >= 1; off >>= 1) v += __shfl_xor(v, off);
        myc[ee] = v;
    }
    int base = 0;
    #pragma unroll
    for (int ee = 0; ee < 8; ++ee) if (ee < e) base += myc[ee];
    if (lane == 0) { cnt[e] = myc[e]; offs[e] = base; }
    // pass 2: deterministic slot assignment via wave prefix scan
    for (int c = 0; c < TOK; c += 64) {
        int t = c + lane;
        int kk = -1;
        if (e01[2 * t] == e) kk = 0;
        else if (e01[2 * t + 1] == e) kk = 1;
        int f = (kk >= 0) ? 1 : 0;
        int sc = f;
        #pragma unroll
        for (int o = 1; o < 64; o <<= 1) {
            int nn = __shfl_up(sc, o);
            if (lane >= o) sc += nn;
        }
        if (kk >= 0) {
            int slot = base + sc - 1;
            tok_of[slot] = t;
            slot_p[slot] = p01[2 * t + kk];
            slot_of[2 * t + kk] = slot;
        }
        base += __shfl(sc, 63);
    }
}

// ---- final MoE combine: out[t] += p0*y[s0] + p1*y[s1] (y bf16) ------
__global__ __launch_bounds__(256) void moe_comb(const u16* __restrict__ yb,
    const int* __restrict__ slot_of, const float* __restrict__ p01,
    float* __restrict__ out)
{
    const int t = blockIdx.x;
    const int c4 = threadIdx.x * 4;
    const int s0 = slot_of[2 * t], s1 = slot_of[2 * t + 1];
    const float p0 = p01[2 * t], p1 = p01[2 * t + 1];
    s16x4 y0 = *(const s16x4*)(yb + (size_t)s0 * HID + c4);
    s16x4 y1 = *(const s16x4*)(yb + (size_t)s1 * HID + c4);
    f32x4 o = *(f32x4*)(out + (size_t)t * HID + c4);
    #pragma unroll
    for (int j = 0; j < 4; ++j)
        o[j] += p0 * b2f((u16)y0[j]) + p1 * b2f((u16)y1[j]);
    *(f32x4*)(out + (size_t)t * HID + c4) = o;
}

__global__ void sentinel_k(float* out) {
    out[blockIdx.x * 256 + threadIdx.x] = 12345.0f;
}

extern "C" void kernel_launch(void* const* d_in, const int* in_sizes, int n_in,
                              void* d_out, int out_size, void* d_ws, size_t ws_size,
                              hipStream_t stream)
{
    (void)in_sizes; (void)n_in; (void)out_size;
    const float* hs    = (const float*)d_in[0];
    const float* ln1w  = (const float*)d_in[1];
    const float* ln1b  = (const float*)d_in[2];
    const float* ln2w  = (const float*)d_in[3];
    const float* ln2b  = (const float*)d_in[4];
    const float* qkvw  = (const float*)d_in[5];
    const float* projw = (const float*)d_in[6];
    const float* rw    = (const float*)d_in[7];
    const float* w1    = (const float*)d_in[8];
    const float* w2    = (const float*)d_in[9];
    float* out = (float*)d_out;
    char* ws = (char*)d_ws;

    size_t o = 0;
    auto alloc = [&](size_t bytes) -> void* {
        void* p = ws + o; o += (bytes + 255) & ~(size_t)255; return p;
    };
    u16*   w1t    = (u16*)alloc((size_t)NEXP * FFN * HID * 2);   // [E][F][H]; early: partials
    u16*   w2t    = (u16*)alloc((size_t)NEXP * HID * FFN * 2);   // [E][H][F]
    u16*   qkvwh  = (u16*)alloc((size_t)QKVO * HID * 2);
    u16*   qkvwl  = (u16*)alloc((size_t)QKVO * HID * 2);
    u16*   projwh = (u16*)alloc((size_t)HID * HID * 2);
    u16*   projwl = (u16*)alloc((size_t)HID * HID * 2);
    u16*   ln1h   = (u16*)alloc((size_t)TOK * HID * 2);          // also attnh
    u16*   ln1l   = (u16*)alloc((size_t)TOK * HID * 2);          // also attnl
    float* qkvf   = (float*)alloc((size_t)TOK * QKVO * 4);       // also ln2f, then yb
    u16*   kTh    = (u16*)alloc((size_t)BATCH * NKVH * SEQ * HDIM * 2);
    u16*   kTl    = (u16*)alloc((size_t)BATCH * NKVH * SEQ * HDIM * 2);
    u16*   vTh    = (u16*)alloc((size_t)BATCH * NKVH * HDIM * SEQ * 2);
    u16*   vTl    = (u16*)alloc((size_t)BATCH * NKVH * HDIM * SEQ * 2);
    float* haf    = (float*)alloc((size_t)TOK * HID * 4);
    u16*   ln2h   = (u16*)alloc((size_t)TOK * HID * 2);
    u16*   a1b    = (u16*)alloc((size_t)TOK * 2 * FFN * 2);
    int*   e01    = (int*)alloc(TOK * 2 * 4);
    float* p01    = (float*)alloc(TOK * 2 * 4);
    int*   cnt    = (int*)alloc(256);
    int*   offs   = (int*)alloc(256);
    int*   tok_of = (int*)alloc(TOK * 2 * 4);
    float* slot_p = (float*)alloc(TOK * 2 * 4);
    int*   slot_of = (int*)alloc(TOK * 2 * 4);
    size_t need = o;

    if (ws_size < need) {
        sentinel_k<<<TOK * HID / 256, 256, 0, stream>>>(out);
        return;
    }

    u16* attnh = ln1h;
    u16* attnl = ln1l;
    float* ln2f = qkvf;
    u16*  yb = (u16*)qkvf;       // 8.4MB, region dead after router_k
    float* part = (float*)w1t;   // 21.6 MB partials; w1t written only later

    // weight prep needed before attention
    split_cast_k<<<QKVO * HID / 4 / 256, 256, 0, stream>>>(qkvw, qkvwh, qkvwl);
    split_cast_k<<<HID * HID / 4 / 256, 256, 0, stream>>>(projw, projwh, projwl);
    // LN1 -> split hi/lo
    ln_k<2><<<TOK, 256, 0, stream>>>(hs, ln1w, ln1b, nullptr, ln1h, ln1l);
    // QKV (3-term, 64x64 tile -> 768 blocks, KU=1)
    gemm_db<0, 3, 0, 2, 1><<<dim3(QKVO / 64, TOK / 64, 1), 256, 0, stream>>>(
        ln1h, ln1l, qkvwh, qkvwl, qkvf, nullptr, nullptr, nullptr, nullptr, nullptr, nullptr,
        TOK, QKVO, HID, HID, HID, QKVO, 0);
    kvprep<<<dim3(SEQ / 64, BATCH * NKVH), 256, 0, stream>>>(qkvf, kTh, kTl, vTh, vTl);
    // split-KV flash attention: 32 q-rows per wave, 256-row kv chunks
    attn_part<<<dim3(NPART, NHEAD, BATCH), 64, 0, stream>>>(
        qkvf, kTh, kTl, vTh, vTl, part);
    attn_comb<<<dim3(SEQ / 16, NHEAD, BATCH), 256, 0, stream>>>(part, attnh, attnl);
    // proj + residual -> haf AND out (3-term, 64x64 tile, KU=1)
    gemm_db<0, 3, 4, 2, 1><<<dim3(HID / 64, TOK / 64, 1), 256, 0, stream>>>(
        attnh, attnl, projwh, projwl, haf, hs, out, nullptr, nullptr, nullptr, nullptr,
        TOK, HID, HID, HID, HID, HID, 0);
    // LN2 -> f32 (router) + hi only (FC1 is 1-term)
    ln_k<4><<<TOK, 256, 0, stream>>>(haf, ln2w, ln2b, ln2f, ln2h, nullptr);
    // MoE weight prep (after partials are dead)
    trans_cast_k<<<dim3(FFN / 64, HID / 64, NEXP), 256, 0, stream>>>(w1, w1t, HID, FFN);
    trans_cast_k<<<dim3(HID / 64, FFN / 64, NEXP), 256, 0, stream>>>(w2, w2t, FFN, HID);
    // router + fused deterministic bucketing (counts + prefix + scatter)
    router_k<<<TOK, 64, 0, stream>>>(ln2f, rw, e01, p01);
    scatter_det<<<NEXP, 64, 0, stream>>>(e01, p01, cnt, offs, tok_of, slot_p, slot_of);
    // FC1 (1-term, gather rows, gelu->bf16, 128x64 tile, KU=2 -> 48KB LDS)
    gemm_db<1, 1, 2, 1, 2><<<dim3(FFN / 64, TOK / 128, NEXP), 256, 0, stream>>>(
        ln2h, nullptr, w1t, nullptr, a1b, nullptr, nullptr, tok_of, offs, cnt, nullptr,
        0, FFN, HID, HID, HID, FFN, (long long)FFN * HID);
    // FC2 (1-term, contig rows, bf16 y store, 128x64 tile, KU=2 -> 48KB LDS)
    gemm_db<2, 1, 5, 1, 2><<<dim3(HID / 64, TOK / 128, NEXP), 256, 0, stream>>>(
        a1b, nullptr, w2t, nullptr, yb, nullptr, nullptr, tok_of, offs, cnt, slot_p,
        0, HID, FFN, FFN, FFN, HID, (long long)HID * FFN);
    // final combine: out += p0*y0 + p1*y1
    moe_comb<<<TOK, 256, 0, stream>>>(yb, slot_of, p01, out);
}

// Round 17
// 305.928 us; speedup vs baseline: 1.1590x; 1.0360x over previous
//
#include <hip/hip_runtime.h>
#include <hip/hip_bf16.h>

typedef unsigned short u16;
typedef __attribute__((ext_vector_type(8))) short s16x8;
typedef __attribute__((ext_vector_type(4))) short s16x4;
typedef __attribute__((ext_vector_type(4))) float f32x4;

#define SEQ 1024
#define BATCH 2
#define HID 1024
#define NHEAD 16
#define NKVH 4
#define HDIM 64
#define NEXP 8
#define FFN 2048
#define TOK (SEQ*BATCH)
#define QKVO ((NHEAD + 2*NKVH)*HDIM)   // 1536
#define NPART 80                        // 32-row q-tiles, 256-row kv chunks
#define PREC 2112                       // 32*64 o + 32 m + 32 l

// async global->LDS, 16B per lane, dest = uniform base + lane*16
#define GL16(gp, lp) __builtin_amdgcn_global_load_lds( \
    (const __attribute__((address_space(1))) unsigned int*)(gp), \
    (__attribute__((address_space(3))) unsigned int*)(lp), 16, 0, 0)

__device__ __forceinline__ float b2f(u16 u) {
    unsigned int x = ((unsigned int)u) << 16;
    return __uint_as_float(x);
}
__device__ __forceinline__ u16 f2b(float f) {
    unsigned int x = __float_as_uint(f);
    x = (x + 0x7FFFu + ((x >> 16) & 1u)) >> 16;
    return (u16)x;
}
__device__ __forceinline__ void split2(float x, u16& hi, u16& lo) {
    hi = f2b(x);
    lo = f2b(x - b2f(hi));
}
__device__ __forceinline__ f32x4 mfma16(s16x8 a, s16x8 b, f32x4 c) {
    return __builtin_amdgcn_mfma_f32_16x16x32_bf16(a, b, c, 0, 0, 0);
}
__device__ __forceinline__ float gelu_t(float x) {
    float x3 = x * x * x;
    return 0.5f * x * (1.0f + tanhf(0.7978845608028654f * (x + 0.044715f * x3)));
}

// ------- LayerNorm: f32 in; OUTMODE: 0=f32, 2=hi/lo, 3=f32+hi/lo, 4=f32+hi -
template<int OUTMODE>
__global__ __launch_bounds__(256) void ln_k(const float* __restrict__ xin,
    const float* __restrict__ wgt, const float* __restrict__ bia,
    float* __restrict__ outf, u16* __restrict__ outh, u16* __restrict__ outl)
{
    __shared__ float red[8];
    const int t = blockIdx.x, tid = threadIdx.x;
    f32x4 u = *((const f32x4*)(xin + (size_t)t * HID) + tid);
    float s = u[0] + u[1] + u[2] + u[3];
    #pragma unroll
    for (int off = 32; off >= 1; off >>= 1) s += __shfl_xor(s, off);
    if ((tid & 63) == 0) red[tid >> 6] = s;
    __syncthreads();
    float mu = (red[0] + red[1] + red[2] + red[3]) * (1.0f / HID);
    float d0 = u[0]-mu, d1 = u[1]-mu, d2 = u[2]-mu, d3 = u[3]-mu;
    float ss = d0*d0 + d1*d1 + d2*d2 + d3*d3;
    #pragma unroll
    for (int off = 32; off >= 1; off >>= 1) ss += __shfl_xor(ss, off);
    if ((tid & 63) == 0) red[4 + (tid >> 6)] = ss;
    __syncthreads();
    float var = (red[4] + red[5] + red[6] + red[7]) * (1.0f / HID);
    float rs = 1.0f / sqrtf(var + 1e-5f);
    f32x4 wv = *((const f32x4*)wgt + tid);
    f32x4 bv = *((const f32x4*)bia + tid);
    f32x4 o;
    o[0] = d0*rs*wv[0] + bv[0];
    o[1] = d1*rs*wv[1] + bv[1];
    o[2] = d2*rs*wv[2] + bv[2];
    o[3] = d3*rs*wv[3] + bv[3];
    if (OUTMODE == 0 || OUTMODE >= 3)
        *((f32x4*)(outf + (size_t)t * HID) + tid) = o;
    if (OUTMODE == 2 || OUTMODE == 3) {
        s16x4 h, l;
        #pragma unroll
        for (int j = 0; j < 4; ++j) {
            u16 hb, lb; split2(o[j], hb, lb);
            h[j] = (short)hb; l[j] = (short)lb;
        }
        *((s16x4*)(outh + (size_t)t * HID) + tid) = h;
        *((s16x4*)(outl + (size_t)t * HID) + tid) = l;
    }
    if (OUTMODE == 4) {
        s16x4 h;
        #pragma unroll
        for (int j = 0; j < 4; ++j) h[j] = (short)f2b(o[j]);
        *((s16x4*)(outh + (size_t)t * HID) + tid) = h;
    }
}

// ---- weight prep: split-cast qkvw AND projw in one launch -----------
__global__ __launch_bounds__(256) void split_cast2_k(
    const float* __restrict__ inA, u16* __restrict__ hiA, u16* __restrict__ loA, int nA4,
    const float* __restrict__ inB, u16* __restrict__ hiB, u16* __restrict__ loB)
{
    int i = blockIdx.x * 256 + threadIdx.x;
    const float* in; u16* hi; u16* lo;
    if (i < nA4) { in = inA; hi = hiA; lo = loA; }
    else { i -= nA4; in = inB; hi = hiB; lo = loB; }
    f32x4 v = ((const f32x4*)in)[i];
    s16x4 h, l;
    #pragma unroll
    for (int j = 0; j < 4; ++j) {
        u16 hb, lb; split2(v[j], hb, lb);
        h[j] = (short)hb; l[j] = (short)lb;
    }
    ((s16x4*)hi)[i] = h;
    ((s16x4*)lo)[i] = l;
}

// -------- weight prep: transpose-cast f32 [E][R][C] -> bf16 [E][C][R]
__global__ __launch_bounds__(256) void trans_cast_k(const float* __restrict__ in,
    u16* __restrict__ out, int R, int C)
{
    __shared__ float tile[64][65];
    const int e = blockIdx.z;
    const float* src = in + (size_t)e * R * C;
    u16* dst = out + (size_t)e * C * R;
    const int r0 = blockIdx.y * 64, c0 = blockIdx.x * 64;
    const int tr = threadIdx.x >> 2, tc = (threadIdx.x & 3) * 16;
    #pragma unroll
    for (int j = 0; j < 4; ++j) {
        f32x4 v = *(const f32x4*)(src + (size_t)(r0 + tr) * C + c0 + tc + j * 4);
        *(f32x4*)&tile[tr][tc + j * 4] = v;
    }
    __syncthreads();
    s16x8 o0, o1;
    #pragma unroll
    for (int j = 0; j < 8; ++j) o0[j] = (short)f2b(tile[tc + j][tr]);
    #pragma unroll
    for (int j = 0; j < 8; ++j) o1[j] = (short)f2b(tile[tc + 8 + j][tr]);
    u16* dp = dst + (size_t)(c0 + tr) * R + r0 + tc;
    *(s16x8*)dp = o0;
    *(s16x8*)(dp + 8) = o1;
}

// ------ gemm_db: bf16 MFMA GEMM, global_load_lds + double buffer -----
// 1-D grid with XCD-aware decode:
//   AMODE==0: xcd=bid&7 owns N-panels [xcd*nx/8,(xcd+1)*nx/8) -> B L2-resident
//   AMODE!=0: e=bid&7 (expert pinned to one XCD; its weights L2-resident)
// TERMS: 1 = AhBh ; 2 = + AlBh ; 3 = + AhBl
// EPI: 0 f32; 1 f32+RES; 2 bf16(gelu); 4 f32+RES dual; 5 bf16 plain
// TILE: 0 = 128x128; 1 = 128x64; 2 = 64x64
// KU: K-chunks (x32) staged per barrier iteration
template<int AMODE, int TERMS, int EPI, int TILE, int KU>
__global__ __launch_bounds__(256, 2) void gemm_db(
    const u16* __restrict__ Ah, const u16* __restrict__ Al,
    const u16* __restrict__ Bh, const u16* __restrict__ Bl,
    void* __restrict__ Cv, const float* __restrict__ RES, float* __restrict__ C2,
    const int* __restrict__ glist, const int* __restrict__ offs,
    const int* __restrict__ cnts, const float* __restrict__ slot_p,
    int M, int N, int K, int lda, int ldb, int ldc, long long bStrideE, int nx)
{
    constexpr int BM = (TILE == 2) ? 64 : 128;
    constexpr int BN = (TILE == 0) ? 128 : 64;
    constexpr int MI = (TILE == 0) ? 4 : ((TILE == 1) ? 2 : 1);
    constexpr bool A2 = (BM == 128);
    constexpr bool B2 = (BN == 128);
    __shared__ u16 AHs[2][KU][BM][32];
    __shared__ u16 ALs[(TERMS >= 2) ? 2 : 1][(TERMS >= 2) ? KU : 1][(TERMS >= 2) ? BM : 1][32];
    __shared__ u16 BHs[2][KU][BN][32];
    __shared__ u16 BLs[(TERMS >= 3) ? 2 : 1][(TERMS >= 3) ? KU : 1][(TERMS >= 3) ? BN : 1][32];

    const int tid = threadIdx.x;
    const int bid = blockIdx.x;
    int m0, n0;
    int off = 0, cnt = M;
    if (AMODE == 0) {
        const int xcd = bid & 7, j = bid >> 3;
        const int npx = nx >> 3;
        n0 = (xcd * npx + j % npx) * BN;
        m0 = (j / npx) * BM;
    } else {
        const int e = bid & 7, j = bid >> 3;
        n0 = (j % nx) * BN;
        m0 = (j / nx) * BM;
        off = offs[e]; cnt = cnts[e];
        if (m0 >= cnt) return;
        long long be = (long long)e * bStrideE;
        Bh += be;
        if (TERMS >= 3) Bl += be;
    }
    const int lane = tid & 63, w = tid >> 6;
    const int wmB = (TILE == 0) ? ((w >> 1) * 64) : (w * (BM / 4));
    const int wnB = (TILE == 0) ? ((w & 1) * 64) : 0;
    const int l16 = lane & 15, grp = lane >> 4;
    const int srow = lane >> 2, schk = (lane & 3) * 8;
    const int lrA = w * (BM / 4);
    const int lrB = w * (BN / 4);

    long long ga0, ga1 = 0;
    {
        int am0 = m0 + lrA + srow;
        int am1 = am0 + 16;
        long long r0, r1;
        if (AMODE == 0) { r0 = am0; r1 = am1; }
        else if (AMODE == 1) {
            r0 = glist[off + ((am0 < cnt) ? am0 : 0)];
            r1 = A2 ? glist[off + ((am1 < cnt) ? am1 : 0)] : 0;
        } else {
            r0 = off + ((am0 < cnt) ? am0 : 0);
            r1 = A2 ? (off + ((am1 < cnt) ? am1 : 0)) : 0;
        }
        ga0 = r0 * lda + schk;
        if (A2) ga1 = r1 * lda + schk;
    }
    const long long gb0 = (long long)(n0 + lrB + srow) * ldb + schk;
    const long long gb1 = gb0 + 16LL * ldb;

    auto stage = [&](int bf, int k0) {
        #pragma unroll
        for (int u = 0; u < KU; ++u) {
            const int ko = k0 + u * 32;
            GL16(Ah + ga0 + ko, &AHs[bf][u][lrA][0]);
            if constexpr (A2) GL16(Ah + ga1 + ko, &AHs[bf][u][lrA + 16][0]);
            if constexpr (TERMS >= 2) {
                GL16(Al + ga0 + ko, &ALs[bf][u][lrA][0]);
                if constexpr (A2) GL16(Al + ga1 + ko, &ALs[bf][u][lrA + 16][0]);
            }
            GL16(Bh + gb0 + ko, &BHs[bf][u][lrB][0]);
            if constexpr (B2) GL16(Bh + gb1 + ko, &BHs[bf][u][lrB + 16][0]);
            if constexpr (TERMS >= 3) {
                GL16(Bl + gb0 + ko, &BLs[bf][u][lrB][0]);
                if constexpr (B2) GL16(Bl + gb1 + ko, &BLs[bf][u][lrB + 16][0]);
            }
        }
    };

    f32x4 acc[MI][4];
    #pragma unroll
    for (int i = 0; i < MI; ++i)
        #pragma unroll
        for (int j = 0; j < 4; ++j) acc[i][j] = f32x4{0.f, 0.f, 0.f, 0.f};

    const int nk = K / (32 * KU);
    int cur = 0;
    stage(0, 0);
    __syncthreads();
    for (int t = 0; t < nk; ++t) {
        if (t + 1 < nk) stage(cur ^ 1, (t + 1) * 32 * KU);
        #pragma unroll
        for (int u = 0; u < KU; ++u) {
            s16x8 ah[MI], al[MI], bh[4], bl[4];
            #pragma unroll
            for (int i = 0; i < MI; ++i)
                ah[i] = *(const s16x8*)&AHs[cur][u][wmB + i * 16 + l16][grp * 8];
            if constexpr (TERMS >= 2) {
                #pragma unroll
                for (int i = 0; i < MI; ++i)
                    al[i] = *(const s16x8*)&ALs[cur][u][wmB + i * 16 + l16][grp * 8];
            }
            #pragma unroll
            for (int j = 0; j < 4; ++j)
                bh[j] = *(const s16x8*)&BHs[cur][u][wnB + j * 16 + l16][grp * 8];
            if constexpr (TERMS >= 3) {
                #pragma unroll
                for (int j = 0; j < 4; ++j)
                    bl[j] = *(const s16x8*)&BLs[cur][u][wnB + j * 16 + l16][grp * 8];
            }
            #pragma unroll
            for (int i = 0; i < MI; ++i) {
                #pragma unroll
                for (int j = 0; j < 4; ++j) {
                    acc[i][j] = mfma16(ah[i], bh[j], acc[i][j]);
                    if constexpr (TERMS >= 3) acc[i][j] = mfma16(ah[i], bl[j], acc[i][j]);
                    if constexpr (TERMS >= 2) acc[i][j] = mfma16(al[i], bh[j], acc[i][j]);
                }
            }
        }
        __syncthreads();
        cur ^= 1;
    }
    // ---- epilogue ----
    #pragma unroll
    for (int i = 0; i < MI; ++i) {
        #pragma unroll
        for (int j = 0; j < 4; ++j) {
            int col = n0 + wnB + j * 16 + l16;
            #pragma unroll
            for (int r = 0; r < 4; ++r) {
                int mr = m0 + wmB + i * 16 + grp * 4 + r;
                if (AMODE != 0 && mr >= cnt) continue;
                long long crow = (AMODE == 0) ? mr : (off + mr);
                float val = acc[i][j][r];
                if (EPI == 0) {
                    ((float*)Cv)[crow * ldc + col] = val;
                } else if (EPI == 1) {
                    ((float*)Cv)[crow * ldc + col] = val + RES[crow * ldc + col];
                } else if (EPI == 2) {
                    ((u16*)Cv)[crow * ldc + col] = f2b(gelu_t(val));
                } else if (EPI == 5) {
                    ((u16*)Cv)[crow * ldc + col] = f2b(val);
                } else {
                    float v2 = val + RES[crow * ldc + col];
                    ((float*)Cv)[crow * ldc + col] = v2;
                    C2[crow * ldc + col] = v2;
                }
            }
        }
    }
}

// -------- K/V prep: K split bf16 (row layout), V^T split bf16 --------
__global__ __launch_bounds__(256) void kvprep(const float* __restrict__ qkvf,
    u16* __restrict__ kTh, u16* __restrict__ kTl,
    u16* __restrict__ vTh, u16* __restrict__ vTl)
{
    __shared__ float tile[64][68];
    const int st = blockIdx.x * 64;
    const int b = blockIdx.y & 1, kvh = blockIdx.y >> 1;
    const int tid = threadIdx.x;
    #pragma unroll
    for (int h = 0; h < 4; ++h) {
        int c = tid + h * 256;
        int srow = c >> 4, dseg = c & 15;
        f32x4 v = *(const f32x4*)(qkvf + (size_t)((st + srow) * BATCH + b) * QKVO
                                  + (NHEAD + NKVH) * HDIM + kvh * HDIM + dseg * 4);
        *(f32x4*)&tile[srow][dseg * 4] = v;
    }
    {
        int row = tid >> 2, qseg = tid & 3;
        const float* kr = qkvf + (size_t)((st + row) * BATCH + b) * QKVO
                          + NHEAD * HDIM + kvh * HDIM + qseg * 16;
        size_t ko = ((size_t)((b * NKVH + kvh) * SEQ + st + row)) * HDIM + qseg * 16;
        #pragma unroll
        for (int c = 0; c < 4; ++c) {
            f32x4 x = *(const f32x4*)(kr + c * 4);
            s16x4 vh, vl;
            #pragma unroll
            for (int j = 0; j < 4; ++j) {
                u16 hb, lb; split2(x[j], hb, lb);
                vh[j] = (short)hb; vl[j] = (short)lb;
            }
            *(s16x4*)(kTh + ko + c * 4) = vh;
            *(s16x4*)(kTl + ko + c * 4) = vl;
        }
    }
    __syncthreads();
    #pragma unroll
    for (int h = 0; h < 2; ++h) {
        int c = tid + h * 256;
        int drow = c >> 3, sseg = c & 7;
        s16x8 vh, vl;
        #pragma unroll
        for (int j = 0; j < 8; ++j) {
            u16 hb, lb; split2(tile[sseg * 8 + j][drow], hb, lb);
            vh[j] = (short)hb; vl[j] = (short)lb;
        }
        size_t oo = ((size_t)((b * NKVH + kvh) * HDIM + drow)) * SEQ + st + sseg * 8;
        *(s16x8*)(vTh + oo) = vh;
        *(s16x8*)(vTl + oo) = vl;
    }
}

// --- Flash attention partials: 1 wave, 32 q-rows, 256-row kv chunk ---
__global__ __launch_bounds__(64, 3) void attn_part(
    const float* __restrict__ qkvf,
    const u16* __restrict__ kTh, const u16* __restrict__ kTl,
    const u16* __restrict__ vTh, const u16* __restrict__ vTl,
    float* __restrict__ part)
{
    __shared__ u16 plh[32][40];
    __shared__ u16 pll[32][40];
    const int p = blockIdx.x;
    int qt, c;
    if (p < 32)      { c = 0; qt = p; }
    else if (p < 56) { c = 1; qt = p - 24; }
    else if (p < 72) { c = 2; qt = p - 40; }
    else             { c = 3; qt = p - 48; }
    const int h = blockIdx.y, b = blockIdx.z;
    const int kvh = h >> 2;
    const int lane = threadIdx.x, l16 = lane & 15, grp = lane >> 4;

    s16x8 qh[2][2], ql[2][2];
    #pragma unroll
    for (int mt = 0; mt < 2; ++mt) {
        const float* qb = qkvf + (size_t)((qt * 32 + mt * 16 + l16) * BATCH + b) * QKVO
                          + h * HDIM + grp * 8;
        #pragma unroll
        for (int ks = 0; ks < 2; ++ks) {
            f32x4 x0 = *(const f32x4*)(qb + ks * 32);
            f32x4 x1 = *(const f32x4*)(qb + ks * 32 + 4);
            #pragma unroll
            for (int j = 0; j < 4; ++j) {
                u16 hb, lb;
                split2(x0[j], hb, lb);
                qh[mt][ks][j] = (short)hb; ql[mt][ks][j] = (short)lb;
                split2(x1[j], hb, lb);
                qh[mt][ks][4 + j] = (short)hb; ql[mt][ks][4 + j] = (short)lb;
            }
        }
    }
    float mrow[2][4], lsum[2][4];
    f32x4 o[2][4];
    #pragma unroll
    for (int mt = 0; mt < 2; ++mt) {
        #pragma unroll
        for (int r = 0; r < 4; ++r) { mrow[mt][r] = -__builtin_inff(); lsum[mt][r] = 0.f; }
        #pragma unroll
        for (int db = 0; db < 4; ++db) o[mt][db] = f32x4{0.f, 0.f, 0.f, 0.f};
    }

    const size_t kvbase = (size_t)(b * NKVH + kvh) * SEQ;
    const int kv0 = c * 256;
    const int kv_hi = min(kv0 + 256, qt * 32 + 32);
    const int nt = (kv_hi - kv0 + 31) >> 5;
    for (int jb = 0; jb < nt; ++jb) {
        const int kvb = kv0 + jb * 32;
        f32x4 s[2][2];
        #pragma unroll
        for (int t2 = 0; t2 < 2; ++t2) {
            size_t kb = (kvbase + kvb + t2 * 16 + l16) * HDIM + grp * 8;
            f32x4 z0 = f32x4{0.f, 0.f, 0.f, 0.f};
            f32x4 z1 = f32x4{0.f, 0.f, 0.f, 0.f};
            #pragma unroll
            for (int ks = 0; ks < 2; ++ks) {
                s16x8 kh = *(const s16x8*)(kTh + kb + ks * 32);
                s16x8 kl = *(const s16x8*)(kTl + kb + ks * 32);
                z0 = mfma16(qh[0][ks], kh, z0);
                z0 = mfma16(qh[0][ks], kl, z0);
                z0 = mfma16(ql[0][ks], kh, z0);
                z1 = mfma16(qh[1][ks], kh, z1);
                z1 = mfma16(qh[1][ks], kl, z1);
                z1 = mfma16(ql[1][ks], kh, z1);
            }
            s[0][t2] = z0; s[1][t2] = z1;
        }
        #pragma unroll
        for (int mt = 0; mt < 2; ++mt) {
            #pragma unroll
            for (int r = 0; r < 4; ++r) {
                const int qrow = qt * 32 + mt * 16 + grp * 4 + r;
                float a0 = s[mt][0][r] * 0.125f; if (kvb + l16 > qrow) a0 = -__builtin_inff();
                float a1 = s[mt][1][r] * 0.125f; if (kvb + 16 + l16 > qrow) a1 = -__builtin_inff();
                float mx = fmaxf(a0, a1);
                #pragma unroll
                for (int t = 1; t < 16; t <<= 1) mx = fmaxf(mx, __shfl_xor(mx, t));
                float mn = fmaxf(mrow[mt][r], mx);
                float sc = __expf(mrow[mt][r] - mn);
                float p0 = __expf(a0 - mn), p1 = __expf(a1 - mn);
                float ps = p0 + p1;
                #pragma unroll
                for (int t = 1; t < 16; t <<= 1) ps += __shfl_xor(ps, t);
                lsum[mt][r] = lsum[mt][r] * sc + ps;
                mrow[mt][r] = mn;
                s[mt][0][r] = p0; s[mt][1][r] = p1;
                #pragma unroll
                for (int db = 0; db < 4; ++db) o[mt][db][r] *= sc;
            }
        }
        __syncthreads();
        #pragma unroll
        for (int mt = 0; mt < 2; ++mt) {
            #pragma unroll
            for (int t2 = 0; t2 < 2; ++t2) {
                #pragma unroll
                for (int r = 0; r < 4; ++r) {
                    u16 hb, lb; split2(s[mt][t2][r], hb, lb);
                    plh[mt * 16 + grp * 4 + r][t2 * 16 + l16] = hb;
                    pll[mt * 16 + grp * 4 + r][t2 * 16 + l16] = lb;
                }
            }
        }
        __syncthreads();
        s16x8 pah0 = *(const s16x8*)&plh[l16][grp * 8];
        s16x8 pal0 = *(const s16x8*)&pll[l16][grp * 8];
        s16x8 pah1 = *(const s16x8*)&plh[16 + l16][grp * 8];
        s16x8 pal1 = *(const s16x8*)&pll[16 + l16][grp * 8];
        #pragma unroll
        for (int db = 0; db < 4; ++db) {
            size_t vo = ((size_t)((b * NKVH + kvh) * HDIM + db * 16 + l16)) * SEQ + kvb + grp * 8;
            s16x8 vh = *(const s16x8*)(vTh + vo);
            s16x8 vl = *(const s16x8*)(vTl + vo);
            o[0][db] = mfma16(pah0, vh, o[0][db]);
            o[0][db] = mfma16(pah0, vl, o[0][db]);
            o[0][db] = mfma16(pal0, vh, o[0][db]);
            o[1][db] = mfma16(pah1, vh, o[1][db]);
            o[1][db] = mfma16(pah1, vl, o[1][db]);
            o[1][db] = mfma16(pal1, vh, o[1][db]);
        }
    }
    float* rec = part + (((size_t)(b * NHEAD + h) * NPART + p) * PREC);
    #pragma unroll
    for (int mt = 0; mt < 2; ++mt) {
        #pragma unroll
        for (int db = 0; db < 4; ++db) {
            #pragma unroll
            for (int r = 0; r < 4; ++r)
                rec[(mt * 16 + grp * 4 + r) * 64 + db * 16 + l16] = o[mt][db][r];
        }
    }
    if (l16 == 0) {
        #pragma unroll
        for (int mt = 0; mt < 2; ++mt) {
            #pragma unroll
            for (int r = 0; r < 4; ++r) {
                rec[2048 + mt * 16 + grp * 4 + r] = mrow[mt][r];
                rec[2080 + mt * 16 + grp * 4 + r] = lsum[mt][r];
            }
        }
    }
}

// ------- combine partials -> split-bf16 attention output -------------
__global__ __launch_bounds__(256) void attn_comb(const float* __restrict__ part,
    u16* __restrict__ attn_h, u16* __restrict__ attn_l)
{
    const int qt16 = blockIdx.x, h = blockIdx.y, b = blockIdx.z;
    const int qt32 = qt16 >> 1;
    const int lrow = (qt16 & 1) * 16 + (threadIdx.x >> 4);
    const int nch = (qt32 >> 3) + 1;
    const int c4 = (threadIdx.x & 15) * 4;
    const size_t base = (size_t)(b * NHEAD + h) * NPART;
    const int pbase[4] = {0, 24, 40, 48};   // p = pbase[c] + qt32
    float mv[4], lv[4];
    float M = -__builtin_inff();
    #pragma unroll
    for (int c = 0; c < 4; ++c) {
        if (c < nch) {
            const float* rec = part + (base + pbase[c] + qt32) * PREC;
            mv[c] = rec[2048 + lrow];
            lv[c] = rec[2080 + lrow];
            M = fmaxf(M, mv[c]);
        }
    }
    float L = 0.f;
    f32x4 acc = f32x4{0.f, 0.f, 0.f, 0.f};
    #pragma unroll
    for (int c = 0; c < 4; ++c) {
        if (c < nch) {
            const float* rec = part + (base + pbase[c] + qt32) * PREC;
            float wgt = __expf(mv[c] - M);
            L += lv[c] * wgt;
            f32x4 ov = *(const f32x4*)(rec + lrow * 64 + c4);
            acc[0] += ov[0] * wgt; acc[1] += ov[1] * wgt;
            acc[2] += ov[2] * wgt; acc[3] += ov[3] * wgt;
        }
    }
    float inv = 1.f / L;
    const int qrow = qt32 * 32 + lrow;
    size_t oo = (size_t)(qrow * BATCH + b) * HID + h * HDIM + c4;
    #pragma unroll
    for (int j = 0; j < 4; ++j) {
        u16 hb, lb; split2(acc[j] * inv, hb, lb);
        attn_h[oo + j] = hb;
        attn_l[oo + j] = lb;
    }
}

// ---------------- Router: logits, softmax, top2 ----------------------
__global__ __launch_bounds__(64) void router_k(const float* __restrict__ ln2,
    const float* __restrict__ rw, int* __restrict__ e01, float* __restrict__ p01)
{
    const int t = blockIdx.x, lane = threadIdx.x;
    const float* xr = ln2 + (size_t)t * HID + lane * 16;
    float x[16];
    #pragma unroll
    for (int c = 0; c < 4; ++c) {
        f32x4 u = *(const f32x4*)(xr + c * 4);
        #pragma unroll
        for (int j = 0; j < 4; ++j) x[c * 4 + j] = u[j];
    }
    float lg[8];
    #pragma unroll
    for (int e = 0; e < 8; ++e) {
        const float* wr = rw + (size_t)e * HID + lane * 16;
        float a = 0.f;
        #pragma unroll
        for (int c = 0; c < 4; ++c) {
            f32x4 wv = *(const f32x4*)(wr + c * 4);
            #pragma unroll
            for (int j = 0; j < 4; ++j) a += x[c * 4 + j] * wv[j];
        }
        #pragma unroll
        for (int off = 32; off >= 1; off >>= 1) a += __shfl_xor(a, off);
        lg[e] = a;
    }
    float mx = lg[0];
    #pragma unroll
    for (int e = 1; e < 8; ++e) mx = fmaxf(mx, lg[e]);
    float pe[8], ssum = 0.f;
    #pragma unroll
    for (int e = 0; e < 8; ++e) { pe[e] = expf(lg[e] - mx); ssum += pe[e]; }
    float inv = 1.f / ssum;
    int e0 = 0; float b0 = -1.f;
    #pragma unroll
    for (int e = 0; e < 8; ++e) { float p = pe[e] * inv; if (p > b0) { b0 = p; e0 = e; } }
    int e1 = -1; float b1 = -1.f;
    #pragma unroll
    for (int e = 0; e < 8; ++e) {
        if (e == e0) continue;
        float p = pe[e] * inv; if (p > b1) { b1 = p; e1 = e; }
    }
    if (lane == 0) {
        e01[2 * t] = e0; e01[2 * t + 1] = e1;
        p01[2 * t] = b0; p01[2 * t + 1] = b1;
    }
}

// --- fused count + prefix + deterministic scatter (8 blocks, 1 wave) -
__global__ __launch_bounds__(64) void scatter_det(const int* __restrict__ e01,
    const float* __restrict__ p01, int* __restrict__ cnt, int* __restrict__ offs,
    int* __restrict__ tok_of, float* __restrict__ slot_p, int* __restrict__ slot_of)
{
    const int e = blockIdx.x;
    const int lane = threadIdx.x;
    int myc[8] = {0, 0, 0, 0, 0, 0, 0, 0};
    for (int i = lane; i < 2 * TOK; i += 64) {
        int ei = e01[i];
        #pragma unroll
        for (int ee = 0; ee < 8; ++ee) myc[ee] += (ei == ee) ? 1 : 0;
    }
    #pragma unroll
    for (int ee = 0; ee < 8; ++ee) {
        int v = myc[ee];
        #pragma unroll
        for (int off = 32; off >= 1; off >>= 1) v += __shfl_xor(v, off);
        myc[ee] = v;
    }
    int base = 0;
    #pragma unroll
    for (int ee = 0; ee < 8; ++ee) if (ee < e) base += myc[ee];
    if (lane == 0) { cnt[e] = myc[e]; offs[e] = base; }
    for (int c = 0; c < TOK; c += 64) {
        int t = c + lane;
        int kk = -1;
        if (e01[2 * t] == e) kk = 0;
        else if (e01[2 * t + 1] == e) kk = 1;
        int f = (kk >= 0) ? 1 : 0;
        int sc = f;
        #pragma unroll
        for (int o = 1; o < 64; o <<= 1) {
            int nn = __shfl_up(sc, o);
            if (lane >= o) sc += nn;
        }
        if (kk >= 0) {
            int slot = base + sc - 1;
            tok_of[slot] = t;
            slot_p[slot] = p01[2 * t + kk];
            slot_of[2 * t + kk] = slot;
        }
        base += __shfl(sc, 63);
    }
}

// ---- final MoE combine: out[t] += p0*y[s0] + p1*y[s1] (y bf16) ------
__global__ __launch_bounds__(256) void moe_comb(const u16* __restrict__ yb,
    const int* __restrict__ slot_of, const float* __restrict__ p01,
    float* __restrict__ out)
{
    const int t = blockIdx.x;
    const int c4 = threadIdx.x * 4;
    const int s0 = slot_of[2 * t], s1 = slot_of[2 * t + 1];
    const float p0 = p01[2 * t], p1 = p01[2 * t + 1];
    s16x4 y0 = *(const s16x4*)(yb + (size_t)s0 * HID + c4);
    s16x4 y1 = *(const s16x4*)(yb + (size_t)s1 * HID + c4);
    f32x4 o = *(f32x4*)(out + (size_t)t * HID + c4);
    #pragma unroll
    for (int j = 0; j < 4; ++j)
        o[j] += p0 * b2f((u16)y0[j]) + p1 * b2f((u16)y1[j]);
    *(f32x4*)(out + (size_t)t * HID + c4) = o;
}

__global__ void sentinel_k(float* out) {
    out[blockIdx.x * 256 + threadIdx.x] = 12345.0f;
}

extern "C" void kernel_launch(void* const* d_in, const int* in_sizes, int n_in,
                              void* d_out, int out_size, void* d_ws, size_t ws_size,
                              hipStream_t stream)
{
    (void)in_sizes; (void)n_in; (void)out_size;
    const float* hs    = (const float*)d_in[0];
    const float* ln1w  = (const float*)d_in[1];
    const float* ln1b  = (const float*)d_in[2];
    const float* ln2w  = (const float*)d_in[3];
    const float* ln2b  = (const float*)d_in[4];
    const float* qkvw  = (const float*)d_in[5];
    const float* projw = (const float*)d_in[6];
    const float* rw    = (const float*)d_in[7];
    const float* w1    = (const float*)d_in[8];
    const float* w2    = (const float*)d_in[9];
    float* out = (float*)d_out;
    char* ws = (char*)d_ws;

    size_t o = 0;
    auto alloc = [&](size_t bytes) -> void* {
        void* p = ws + o; o += (bytes + 255) & ~(size_t)255; return p;
    };
    u16*   w1t    = (u16*)alloc((size_t)NEXP * FFN * HID * 2);   // [E][F][H]; early: partials
    u16*   w2t    = (u16*)alloc((size_t)NEXP * HID * FFN * 2);   // [E][H][F]
    u16*   qkvwh  = (u16*)alloc((size_t)QKVO * HID * 2);
    u16*   qkvwl  = (u16*)alloc((size_t)QKVO * HID * 2);
    u16*   projwh = (u16*)alloc((size_t)HID * HID * 2);
    u16*   projwl = (u16*)alloc((size_t)HID * HID * 2);
    u16*   ln1h   = (u16*)alloc((size_t)TOK * HID * 2);          // also attnh
    u16*   ln1l   = (u16*)alloc((size_t)TOK * HID * 2);          // also attnl
    float* qkvf   = (float*)alloc((size_t)TOK * QKVO * 4);       // also ln2f, then yb
    u16*   kTh    = (u16*)alloc((size_t)BATCH * NKVH * SEQ * HDIM * 2);
    u16*   kTl    = (u16*)alloc((size_t)BATCH * NKVH * SEQ * HDIM * 2);
    u16*   vTh    = (u16*)alloc((size_t)BATCH * NKVH * HDIM * SEQ * 2);
    u16*   vTl    = (u16*)alloc((size_t)BATCH * NKVH * HDIM * SEQ * 2);
    float* haf    = (float*)alloc((size_t)TOK * HID * 4);
    u16*   ln2h   = (u16*)alloc((size_t)TOK * HID * 2);
    u16*   a1b    = (u16*)alloc((size_t)TOK * 2 * FFN * 2);
    int*   e01    = (int*)alloc(TOK * 2 * 4);
    float* p01    = (float*)alloc(TOK * 2 * 4);
    int*   cnt    = (int*)alloc(256);
    int*   offs   = (int*)alloc(256);
    int*   tok_of = (int*)alloc(TOK * 2 * 4);
    float* slot_p = (float*)alloc(TOK * 2 * 4);
    int*   slot_of = (int*)alloc(TOK * 2 * 4);
    size_t need = o;

    if (ws_size < need) {
        sentinel_k<<<TOK * HID / 256, 256, 0, stream>>>(out);
        return;
    }

    u16* attnh = ln1h;
    u16* attnl = ln1l;
    float* ln2f = qkvf;
    u16*  yb = (u16*)qkvf;       // 8.4MB, region dead after router_k
    float* part = (float*)w1t;   // 21.6 MB partials; w1t written only later

    // weight prep needed before attention (fused: qkvw + projw)
    split_cast2_k<<<(QKVO * HID + HID * HID) / 4 / 256, 256, 0, stream>>>(
        qkvw, qkvwh, qkvwl, QKVO * HID / 4, projw, projwh, projwl);
    // LN1 -> split hi/lo
    ln_k<2><<<TOK, 256, 0, stream>>>(hs, ln1w, ln1b, nullptr, ln1h, ln1l);
    // QKV (3-term, 64x64 tile, 1-D grid + XCD N-panel pinning)
    gemm_db<0, 3, 0, 2, 1><<<(QKVO / 64) * (TOK / 64), 256, 0, stream>>>(
        ln1h, ln1l, qkvwh, qkvwl, qkvf, nullptr, nullptr, nullptr, nullptr, nullptr, nullptr,
        TOK, QKVO, HID, HID, HID, QKVO, 0, QKVO / 64);
    kvprep<<<dim3(SEQ / 64, BATCH * NKVH), 256, 0, stream>>>(qkvf, kTh, kTl, vTh, vTl);
    // split-KV flash attention: 32 q-rows per wave, 256-row kv chunks
    attn_part<<<dim3(NPART, NHEAD, BATCH), 64, 0, stream>>>(
        qkvf, kTh, kTl, vTh, vTl, part);
    attn_comb<<<dim3(SEQ / 16, NHEAD, BATCH), 256, 0, stream>>>(part, attnh, attnl);
    // proj + residual -> haf AND out (3-term, 64x64 tile, XCD pinned)
    gemm_db<0, 3, 4, 2, 1><<<(HID / 64) * (TOK / 64), 256, 0, stream>>>(
        attnh, attnl, projwh, projwl, haf, hs, out, nullptr, nullptr, nullptr, nullptr,
        TOK, HID, HID, HID, HID, HID, 0, HID / 64);
    // LN2 -> f32 (router) + hi only (FC1 is 1-term)
    ln_k<4><<<TOK, 256, 0, stream>>>(haf, ln2w, ln2b, ln2f, ln2h, nullptr);
    // MoE weight prep (after partials are dead)
    trans_cast_k<<<dim3(FFN / 64, HID / 64, NEXP), 256, 0, stream>>>(w1, w1t, HID, FFN);
    trans_cast_k<<<dim3(HID / 64, FFN / 64, NEXP), 256, 0, stream>>>(w2, w2t, FFN, HID);
    // router + fused deterministic bucketing (counts + prefix + scatter)
    router_k<<<TOK, 64, 0, stream>>>(ln2f, rw, e01, p01);
    scatter_det<<<NEXP, 64, 0, stream>>>(e01, p01, cnt, offs, tok_of, slot_p, slot_of);
    // FC1 (1-term, gather rows, gelu->bf16, 128x64, expert->XCD pinned)
    gemm_db<1, 1, 2, 1, 2><<<NEXP * (FFN / 64) * (TOK / 128), 256, 0, stream>>>(
        ln2h, nullptr, w1t, nullptr, a1b, nullptr, nullptr, tok_of, offs, cnt, nullptr,
        0, FFN, HID, HID, HID, FFN, (long long)FFN * HID, FFN / 64);
    // FC2 (1-term, contig rows, bf16 y store, 128x64, expert->XCD pinned)
    gemm_db<2, 1, 5, 1, 2><<<NEXP * (HID / 64) * (TOK / 128), 256, 0, stream>>>(
        a1b, nullptr, w2t, nullptr, yb, nullptr, nullptr, tok_of, offs, cnt, slot_p,
        0, HID, FFN, FFN, FFN, HID, (long long)HID * FFN, HID / 64);
    // final combine: out += p0*y0 + p1*y1
    moe_comb<<<TOK, 256, 0, stream>>>(yb, slot_of, p01, out);
}